// Round 1
// baseline (836.640 us; speedup 1.0000x reference)
//
#include <hip/hip_runtime.h>
#include <math.h>

// Problem constants
#define B_   32
#define T_   256
#define DV_  1024
#define DJ_  512
#define L_   20
#define T0_  127
#define T1_  62
#define T2_  30
#define TP_  219          // 127+62+30
#define LAM_ 4.0f
#define MARGIN_ 0.1f

// ---------------------------------------------------------------------------
// Weight reorder: conv_w [co][ci][k] -> Wr [co][k][ci]  (GEMM K-dim = k*Cin+ci)
// ---------------------------------------------------------------------------
__global__ void reorder_w_k(const float* __restrict__ src, float* __restrict__ dst,
                            int Cin, int total) {
  int idx = blockIdx.x * 256 + threadIdx.x;
  if (idx >= total) return;
  int KC = Cin * 4;
  int co = idx / KC, rem = idx % KC;
  int k = rem / Cin, ci = rem % Cin;
  dst[idx] = src[(co * Cin + ci) * 4 + k];
}

// ---------------------------------------------------------------------------
// BatchNorm stats, two stage (deterministic, no atomics).
// x layout: [rows][C] channel-contiguous. block = C/4 threads.
// ---------------------------------------------------------------------------
__global__ void stats_partial_k(const float* __restrict__ x, float* __restrict__ part,
                                int C, int rows, int rpg) {
  int rg = blockIdx.x, t = threadIdx.x;
  int r0 = rg * rpg, r1 = min(r0 + rpg, rows);
  float4 s = {0.f,0.f,0.f,0.f}, q = {0.f,0.f,0.f,0.f};
  for (int r = r0; r < r1; ++r) {
    float4 v = *reinterpret_cast<const float4*>(&x[(size_t)r * C + t * 4]);
    s.x += v.x; s.y += v.y; s.z += v.z; s.w += v.w;
    q.x += v.x*v.x; q.y += v.y*v.y; q.z += v.z*v.z; q.w += v.w*v.w;
  }
  float* ps = part + (size_t)rg * 2 * C;
  reinterpret_cast<float4*>(ps)[t] = s;
  reinterpret_cast<float4*>(ps + C)[t] = q;
}

__global__ void stats_final_k(const float* __restrict__ part, float* __restrict__ ms,
                              int C, int ng, float inv_n) {
  int c = blockIdx.x * 256 + threadIdx.x;
  if (c >= C) return;
  float s = 0.f, q = 0.f;
  for (int g = 0; g < ng; ++g) {
    s += part[(size_t)g * 2 * C + c];
    q += part[(size_t)g * 2 * C + C + c];
  }
  float m = s * inv_n;
  float var = q * inv_n - m * m;
  ms[c] = m;
  ms[C + c] = rsqrtf(var + 1e-5f);
}

// ---------------------------------------------------------------------------
// Generic conv-as-GEMM (fp32, 64x64 tile, BK=32, 256 thr, 4x4 micro-tile).
// A row m=(b,to): x[b][t_off_in + to*stride + k][ci]  (input layout [b][T][Cin])
// B row n: Wr[n][k*Cin+ci]
// out[(b*219 + t_off_out + to)*ldout + n]  (+bias, relu optional)
// IN_BN: apply (x-mean)*rstd per input channel during A staging (conv0).
// ---------------------------------------------------------------------------
template<bool IN_BN, bool RELU, bool BIAS>
__global__ __launch_bounds__(256) void conv_gemm_k(
    const float* __restrict__ xin, const float* __restrict__ Wr,
    const float* __restrict__ bias, const float* __restrict__ bn_ms,
    float* __restrict__ out,
    int Cin, int KS, int stride, int b_stride, int t_off_in,
    int To, int M, int t_off_out, int ldout)
{
  __shared__ float As[32][68];   // [kk][m], row stride 68 floats (16B aligned rows)
  __shared__ float Bs[32][68];   // [kk][n]
  int tid = threadIdx.x;
  int tx = tid & 15, ty = tid >> 4;
  int mbase = blockIdx.x * 64, nbase = blockIdx.y * 64;
  int Ktot = KS * Cin;

  float acc[4][4] = {};

  for (int k0 = 0; k0 < Ktot; k0 += 32) {
    int kseg = k0 / Cin, ci0 = k0 % Cin;  // BK=32 chunk lies within one k segment
    // stage A (64 rows x 32 k)
#pragma unroll
    for (int it = 0; it < 2; ++it) {
      int g = tid + it * 256;
      int m_l = g >> 3, kk4 = (g & 7) << 2;
      int m = mbase + m_l;
      float4 v = {0.f,0.f,0.f,0.f};
      if (m < M) {
        int b = m / To, to = m % To;
        int tin = t_off_in + to * stride + kseg;
        v = *reinterpret_cast<const float4*>(
              &xin[(size_t)b * b_stride + (size_t)tin * Cin + ci0 + kk4]);
        if (IN_BN) {
          int c = ci0 + kk4;
          v.x = (v.x - bn_ms[c+0]) * bn_ms[Cin+c+0];
          v.y = (v.y - bn_ms[c+1]) * bn_ms[Cin+c+1];
          v.z = (v.z - bn_ms[c+2]) * bn_ms[Cin+c+2];
          v.w = (v.w - bn_ms[c+3]) * bn_ms[Cin+c+3];
        }
      }
      As[kk4+0][m_l] = v.x; As[kk4+1][m_l] = v.y;
      As[kk4+2][m_l] = v.z; As[kk4+3][m_l] = v.w;
    }
    // stage B (64 cols x 32 k)
#pragma unroll
    for (int it = 0; it < 2; ++it) {
      int g = tid + it * 256;
      int n_l = g >> 3, kk4 = (g & 7) << 2;
      int n = nbase + n_l;
      float4 v = *reinterpret_cast<const float4*>(&Wr[(size_t)n * Ktot + k0 + kk4]);
      Bs[kk4+0][n_l] = v.x; Bs[kk4+1][n_l] = v.y;
      Bs[kk4+2][n_l] = v.z; Bs[kk4+3][n_l] = v.w;
    }
    __syncthreads();
#pragma unroll
    for (int kk = 0; kk < 32; ++kk) {
      float4 a = *reinterpret_cast<const float4*>(&As[kk][ty * 4]);
      float4 b = *reinterpret_cast<const float4*>(&Bs[kk][tx * 4]);
      acc[0][0] += a.x*b.x; acc[0][1] += a.x*b.y; acc[0][2] += a.x*b.z; acc[0][3] += a.x*b.w;
      acc[1][0] += a.y*b.x; acc[1][1] += a.y*b.y; acc[1][2] += a.y*b.z; acc[1][3] += a.y*b.w;
      acc[2][0] += a.z*b.x; acc[2][1] += a.z*b.y; acc[2][2] += a.z*b.z; acc[2][3] += a.z*b.w;
      acc[3][0] += a.w*b.x; acc[3][1] += a.w*b.y; acc[3][2] += a.w*b.z; acc[3][3] += a.w*b.w;
    }
    __syncthreads();
  }

#pragma unroll
  for (int i = 0; i < 4; ++i) {
    int m = mbase + ty * 4 + i;
    if (m >= M) continue;
    int b = m / To, to = m % To;
    float* orow = out + ((size_t)b * TP_ + t_off_out + to) * ldout + nbase + tx * 4;
#pragma unroll
    for (int j = 0; j < 4; ++j) {
      float v = acc[i][j];
      if (BIAS) v += bias[nbase + tx * 4 + j];
      if (RELU) v = fmaxf(v, 0.f);
      orow[j] = v;
    }
  }
}

// ---------------------------------------------------------------------------
// Normalize v2 in place (BN over (b,t)) and compute row norms vn.
// one block per row, 64 threads, 8 channels each.
// ---------------------------------------------------------------------------
__global__ void v2_norm_vn_k(float* __restrict__ v2, const float* __restrict__ ms,
                             float* __restrict__ vn) {
  int r = blockIdx.x, t = threadIdx.x;
  float* row = v2 + (size_t)r * DJ_;
  float ss = 0.f;
#pragma unroll
  for (int h = 0; h < 2; ++h) {
    int c4 = t + h * 64;
    float4 v = reinterpret_cast<float4*>(row)[c4];
    int c = c4 * 4;
    v.x = (v.x - ms[c+0]) * ms[DJ_+c+0];
    v.y = (v.y - ms[c+1]) * ms[DJ_+c+1];
    v.z = (v.z - ms[c+2]) * ms[DJ_+c+2];
    v.w = (v.w - ms[c+3]) * ms[DJ_+c+3];
    reinterpret_cast<float4*>(row)[c4] = v;
    ss += v.x*v.x + v.y*v.y + v.z*v.z + v.w*v.w;
  }
#pragma unroll
  for (int o = 32; o; o >>= 1) ss += __shfl_down(ss, o, 64);
  if (t == 0) vn[r] = sqrtf(ss);
}

// words normalize (elementwise, per-channel affine)
__global__ void wnorm_k(const float* __restrict__ words, const float* __restrict__ ms,
                        float* __restrict__ wbn) {
  int idx = blockIdx.x * 256 + threadIdx.x;
  if (idx >= (B_ * L_ * DJ_) / 4) return;
  int c = (idx & 127) * 4;
  float4 v = reinterpret_cast<const float4*>(words)[idx];
  v.x = (v.x - ms[c+0]) * ms[DJ_+c+0];
  v.y = (v.y - ms[c+1]) * ms[DJ_+c+1];
  v.z = (v.z - ms[c+2]) * ms[DJ_+c+2];
  v.w = (v.w - ms[c+3]) * ms[DJ_+c+3];
  reinterpret_cast<float4*>(wbn)[idx] = v;
}

// Per-sentence Gram matrices G[i][l][l'] = w_l . w_l'
__global__ void gram_k(const float* __restrict__ wbn, float* __restrict__ G) {
  __shared__ float sw[L_ * 516];   // padded stride vs bank conflicts
  int i = blockIdx.x, tid = threadIdx.x;
  for (int idx = tid; idx < L_ * DJ_; idx += 256) {
    int l = idx >> 9, d = idx & 511;
    sw[l * 516 + d] = wbn[(size_t)i * L_ * DJ_ + idx];
  }
  __syncthreads();
  for (int p = tid; p < L_ * L_; p += 256) {
    int l = p / L_, l2 = p % L_;
    const float4* a = reinterpret_cast<const float4*>(&sw[l * 516]);
    const float4* b = reinterpret_cast<const float4*>(&sw[l2 * 516]);
    float acc = 0.f;
    for (int d4 = 0; d4 < 128; ++d4) {
      float4 av = a[d4], bv = b[d4];
      acc += av.x*bv.x + av.y*bv.y + av.z*bv.z + av.w*bv.w;
    }
    G[i * 400 + p] = acc;
  }
}

// ---------------------------------------------------------------------------
// sim kernel: per (i,j) block, thread t handles frame t.
//   a_l = A[(j,t)][i*20+l]; p = softmax(4a masked); num = p.a;
//   vsn^2 = p^T G[i] p; sim = num / (max(vn,eps)*max(vsn,eps))
//   scores[i][j] = max_t sim ; pos_map[i][t] = sim when i==j
// ---------------------------------------------------------------------------
__global__ __launch_bounds__(256) void sim_k(
    const float* __restrict__ A, const float* __restrict__ G,
    const float* __restrict__ vn, const float* __restrict__ wmask,
    float* __restrict__ pos, float* __restrict__ scores) {
  int j = blockIdx.x, i = blockIdx.y;
  __shared__ float sG[400];
  __shared__ float sm[20];
  __shared__ float red[4];
  int tid = threadIdx.x;
  for (int p = tid; p < 400; p += 256) sG[p] = G[i * 400 + p];
  if (tid < 20) sm[tid] = wmask[i * 20 + tid];
  __syncthreads();

  float simv = -1e30f;
  if (tid < TP_) {
    const float* ar = A + ((size_t)j * TP_ + tid) * 640 + i * 20;
    float a[20], p[20];
    float mx = -1e30f;
#pragma unroll
    for (int l = 0; l < 20; ++l) {
      a[l] = ar[l];
      float lg = (sm[l] > 0.5f) ? LAM_ * a[l] : -1e9f;
      p[l] = lg;
      mx = fmaxf(mx, lg);
    }
    float Z = 0.f;
#pragma unroll
    for (int l = 0; l < 20; ++l) { p[l] = __expf(p[l] - mx); Z += p[l]; }
    float invZ = 1.f / Z, num = 0.f;
#pragma unroll
    for (int l = 0; l < 20; ++l) { p[l] *= invZ; num += p[l] * a[l]; }
    float q2 = 0.f;
#pragma unroll
    for (int l = 0; l < 20; ++l) {
      float gi = 0.f;
#pragma unroll
      for (int l2 = 0; l2 < 20; ++l2) gi += sG[l * 20 + l2] * p[l2];
      q2 += p[l] * gi;
    }
    float vnv = fmaxf(vn[(size_t)j * TP_ + tid], 1e-8f);
    float vsnv = fmaxf(sqrtf(q2), 1e-8f);
    simv = num / (vnv * vsnv);
    if (i == j) pos[i * TP_ + tid] = simv;
  }
  // block max over t
  float mv = simv;
#pragma unroll
  for (int o = 32; o; o >>= 1) mv = fmaxf(mv, __shfl_down(mv, o, 64));
  if ((tid & 63) == 0) red[tid >> 6] = mv;
  __syncthreads();
  if (tid == 0)
    scores[i * 32 + j] = fmaxf(fmaxf(red[0], red[1]), fmaxf(red[2], red[3]));
}

// margin ranking loss over scores[32][32]
__global__ void loss_k(const float* __restrict__ scores, float* __restrict__ out) {
  __shared__ float red[16];
  int tid = threadIdx.x;           // 1024 threads = 32x32
  int i = tid >> 5, j = tid & 31;
  float s = scores[tid];
  float dgi = scores[i * 32 + i], dgj = scores[j * 32 + j];
  float c = 0.f;
  if (i != j)
    c = fmaxf(0.f, MARGIN_ + s - dgi) + fmaxf(0.f, MARGIN_ + s - dgj);
#pragma unroll
  for (int o = 32; o; o >>= 1) c += __shfl_down(c, o, 64);
  if ((tid & 63) == 0) red[tid >> 6] = c;
  __syncthreads();
  if (tid == 0) {
    float t = 0.f;
    for (int w = 0; w < 16; ++w) t += red[w];
    out[0] = t / 32.f;
  }
}

// ---------------------------------------------------------------------------
extern "C" void kernel_launch(void* const* d_in, const int* in_sizes, int n_in,
                              void* d_out, int out_size, void* d_ws, size_t ws_size,
                              hipStream_t stream) {
  const float* video = (const float*)d_in[0];
  const float* words = (const float*)d_in[1];
  const float* wmask = (const float*)d_in[2];
  const float* c0w = (const float*)d_in[3];
  const float* c0b = (const float*)d_in[4];
  const float* c1w = (const float*)d_in[5];
  const float* c1b = (const float*)d_in[6];
  const float* c2w = (const float*)d_in[7];
  const float* c2b = (const float*)d_in[8];
  const float* pww = (const float*)d_in[9];   // conv1d_w [512][512][1] == [co][ci]
  const float* pwb = (const float*)d_in[10];
  float* out = (float*)d_out;
  float* ws  = (float*)d_ws;

  // workspace layout (floats) — total ~16.42M floats ≈ 63 MiB
  float* W0r    = ws;                  // 512*4096
  float* W1r    = W0r + 2097152;       // 512*2048
  float* W2r    = W1r + 1048576;       // 512*2048
  float* vcat   = W2r + 1048576;       // 32*219*512 (conv0 t<127 | conv1 127..188 | conv2 189..218)
  float* v2     = vcat + 3588096;      // 32*219*512
  float* wbn    = v2 + 3588096;        // 32*20*512
  float* Amat   = wbn + 327680;        // 7008*640
  float* G      = Amat + 4485120;      // 32*400
  float* vn     = G + 12800;           // 7008
  float* scores = vn + 7008;           // 1024
  float* vpart  = scores + 1024;       // 64*2048
  float* vms    = vpart + 131072;      // 2048
  float* v2part = vms + 2048;          // 64*1024
  float* v2ms   = v2part + 65536;      // 1024
  float* wpart  = v2ms + 1024;         // 16*1024
  float* wms    = wpart + 16384;       // 1024

  // weight reorder [co][ci][k] -> [co][k][ci]
  reorder_w_k<<<(2097152 + 255) / 256, 256, 0, stream>>>(c0w, W0r, 1024, 2097152);
  reorder_w_k<<<(1048576 + 255) / 256, 256, 0, stream>>>(c1w, W1r, 512, 1048576);
  reorder_w_k<<<(1048576 + 255) / 256, 256, 0, stream>>>(c2w, W2r, 512, 1048576);

  // video BN stats (per DV channel over 32*256 rows)
  stats_partial_k<<<64, 256, 0, stream>>>(video, vpart, 1024, 8192, 128);
  stats_final_k<<<4, 256, 0, stream>>>(vpart, vms, 1024, 64, 1.f / 8192.f);

  // conv tower (BN fused into conv0 input staging); outputs concat into vcat
  conv_gemm_k<true,  true,  true><<<dim3(64, 8), 256, 0, stream>>>(
      video, W0r, c0b, vms, vcat, 1024, 4, 2, 256 * 1024, 0, T0_, 32 * T0_, 0, 512);
  conv_gemm_k<false, true,  true><<<dim3(31, 8), 256, 0, stream>>>(
      vcat, W1r, c1b, nullptr, vcat, 512, 4, 2, 219 * 512, 0, T1_, 32 * T1_, T0_, 512);
  conv_gemm_k<false, true,  true><<<dim3(15, 8), 256, 0, stream>>>(
      vcat, W2r, c2b, nullptr, vcat, 512, 4, 2, 219 * 512, T0_, T2_, 32 * T2_, T0_ + T1_, 512);
  // pointwise conv -> v2
  conv_gemm_k<false, false, true><<<dim3(110, 8), 256, 0, stream>>>(
      vcat, pww, pwb, nullptr, v2, 512, 1, 1, 219 * 512, 0, TP_, 32 * TP_, 0, 512);

  // v2 BN (+ row norms)
  stats_partial_k<<<64, 128, 0, stream>>>(v2, v2part, 512, 7008, 110);
  stats_final_k<<<2, 256, 0, stream>>>(v2part, v2ms, 512, 64, 1.f / 7008.f);
  v2_norm_vn_k<<<7008, 64, 0, stream>>>(v2, v2ms, vn);

  // words BN
  stats_partial_k<<<16, 128, 0, stream>>>(words, wpart, 512, 640, 40);
  stats_final_k<<<2, 256, 0, stream>>>(wpart, wms, 512, 16, 1.f / 640.f);
  wnorm_k<<<(81920 + 255) / 256, 256, 0, stream>>>(words, wms, wbn);
  gram_k<<<32, 256, 0, stream>>>(wbn, G);

  // A[(j,t)][(i,l)] = v . w   (GEMM M=7008, N=640, K=512)
  conv_gemm_k<false, false, false><<<dim3(110, 10), 256, 0, stream>>>(
      v2, wbn, nullptr, nullptr, Amat, 512, 1, 1, 219 * 512, 0, TP_, 32 * TP_, 0, 640);

  // fused softmax / cosine-sim / scores / positive_map
  sim_k<<<dim3(32, 32), 256, 0, stream>>>(Amat, G, vn, wmask, out + 1, scores);
  loss_k<<<1, 1024, 0, stream>>>(scores, out);
}

// Round 2
// 353.435 us; speedup vs baseline: 2.3672x; 2.3672x over previous
//
#include <hip/hip_runtime.h>
#include <math.h>

// Problem constants
#define B_   32
#define T_   256
#define DV_  1024
#define DJ_  512
#define L_   20
#define T0_  127
#define T1_  62
#define T2_  30
#define TP_  219          // 127+62+30
#define LAM_ 4.0f
#define MARGIN_ 0.1f

typedef __attribute__((ext_vector_type(8))) short short8;
typedef __attribute__((ext_vector_type(4))) float f32x4;

static __device__ __forceinline__ unsigned short f2bf(float f) {
  union { float f; unsigned u; } v; v.f = f;
  unsigned r = v.u + 0x7fff + ((v.u >> 16) & 1);   // round-to-nearest-even
  return (unsigned short)(r >> 16);
}

struct ushort4_t { unsigned short x, y, z, w; };

#define GLOAD_LDS16(gp, lp)                                                      \
  __builtin_amdgcn_global_load_lds(                                              \
      (const __attribute__((address_space(1))) void*)(gp),                       \
      (__attribute__((address_space(3))) void*)(lp), 16, 0, 0)

// ---------------------------------------------------------------------------
// Weight reorder+cast: conv_w [co][ci][k] -> Wr_bf16 [co][k*Cin+ci]
// ---------------------------------------------------------------------------
__global__ void reorder_w_bf_k(const float* __restrict__ src,
                               unsigned short* __restrict__ dst,
                               int Cin, int KS, int total) {
  int idx = blockIdx.x * 256 + threadIdx.x;
  if (idx >= total) return;
  int KC = Cin * KS;
  int co = idx / KC, rem = idx % KC;
  int k = rem / Cin, ci = rem % Cin;
  dst[idx] = f2bf(src[(co * Cin + ci) * KS + k]);
}

// ---------------------------------------------------------------------------
// BatchNorm stats, two stage (deterministic, no atomics).
// ---------------------------------------------------------------------------
__global__ void stats_partial_k(const float* __restrict__ x, float* __restrict__ part,
                                int C, int rows, int rpg) {
  int rg = blockIdx.x, t = threadIdx.x;
  int r0 = rg * rpg, r1 = min(r0 + rpg, rows);
  float4 s = {0.f,0.f,0.f,0.f}, q = {0.f,0.f,0.f,0.f};
  for (int r = r0; r < r1; ++r) {
    float4 v = *reinterpret_cast<const float4*>(&x[(size_t)r * C + t * 4]);
    s.x += v.x; s.y += v.y; s.z += v.z; s.w += v.w;
    q.x += v.x*v.x; q.y += v.y*v.y; q.z += v.z*v.z; q.w += v.w*v.w;
  }
  float* ps = part + (size_t)rg * 2 * C;
  reinterpret_cast<float4*>(ps)[t] = s;
  reinterpret_cast<float4*>(ps + C)[t] = q;
}

__global__ void stats_final_k(const float* __restrict__ part, float* __restrict__ ms,
                              int C, int ng, float inv_n) {
  int c = blockIdx.x * 256 + threadIdx.x;
  if (c >= C) return;
  float s = 0.f, q = 0.f;
  for (int g = 0; g < ng; ++g) {
    s += part[(size_t)g * 2 * C + c];
    q += part[(size_t)g * 2 * C + C + c];
  }
  float m = s * inv_n;
  float var = q * inv_n - m * m;
  ms[c] = m;
  ms[C + c] = rsqrtf(var + 1e-5f);
}

// video BN apply + cast to bf16.  8.39M elems, float4 per thread.
__global__ void vid_bn_cast_k(const float* __restrict__ video,
                              const float* __restrict__ ms,
                              unsigned short* __restrict__ vbf) {
  int i4 = blockIdx.x * 256 + threadIdx.x;       // < 2097152
  float4 v = reinterpret_cast<const float4*>(video)[i4];
  int c = (i4 & 255) * 4;                        // 1024 channels
  v.x = (v.x - ms[c+0]) * ms[1024+c+0];
  v.y = (v.y - ms[c+1]) * ms[1024+c+1];
  v.z = (v.z - ms[c+2]) * ms[1024+c+2];
  v.w = (v.w - ms[c+3]) * ms[1024+c+3];
  ushort4_t h = { f2bf(v.x), f2bf(v.y), f2bf(v.z), f2bf(v.w) };
  reinterpret_cast<ushort4_t*>(vbf)[i4] = h;
}

// ---------------------------------------------------------------------------
// MFMA bf16 GEMM (conv-as-GEMM via sliding-window im2col collapse).
// BM=128, BN=64, BK=32, 256 thr (4 waves 2x2), wave tile 64x32 (4x2 frags).
// A row m=(b,to): bf16 xin at rowbase(m) + k, k contiguous over KS*Cin.
// B row n: Wr[n*Ktot + k].
// out[(b*TP_ + t_off_out + to)*ldout + n]  (+bias / relu / bf16-out optional)
// ---------------------------------------------------------------------------
template<bool RELU, bool BIAS, bool OUT_BF16>
__global__ __launch_bounds__(256) void mfma_gemm_k(
    const unsigned short* __restrict__ xin, const unsigned short* __restrict__ Wr,
    const float* __restrict__ bias, void* __restrict__ out,
    int b_stride, int row_off, int row_t_stride,
    int To, int M, int t_off_out, int ldout, int Ktot)
{
  __shared__ __align__(16) short As[2][128 * 32];
  __shared__ __align__(16) short Bs[2][64 * 32];

  const int tid  = threadIdx.x;
  const int lane = tid & 63;
  const int wv   = tid >> 6;       // wave 0..3
  const int wr   = wv >> 1;        // wave row (M)
  const int wc   = wv & 1;         // wave col (N)
  const int mbase = blockIdx.x * 128;
  const int nbase = blockIdx.y * 64;

  // ---- per-thread staging source addresses (fixed rows; advance by k0) ----
  const int srow = tid >> 2;            // 0..63
  const int sb   = (tid & 3) * 8;       // element offset within 32-k chunk
  int ma0 = min(mbase + srow,      M - 1);
  int ma1 = min(mbase + srow + 64, M - 1);
  int b0 = ma0 / To, t0 = ma0 % To;
  int b1 = ma1 / To, t1 = ma1 % To;
  const unsigned short* agp0 = xin + (size_t)b0 * b_stride + row_off + (size_t)t0 * row_t_stride + sb;
  const unsigned short* agp1 = xin + (size_t)b1 * b_stride + row_off + (size_t)t1 * row_t_stride + sb;
  const unsigned short* bgp  = Wr + (size_t)(nbase + srow) * Ktot + sb;

  f32x4 acc[4][2] = {};

  const int nsteps = Ktot >> 5;

#define STAGE(buf, k0)                                                   \
  do {                                                                   \
    GLOAD_LDS16(agp0 + (k0), &As[buf][wv * 512]);                        \
    GLOAD_LDS16(agp1 + (k0), &As[buf][2048 + wv * 512]);                 \
    GLOAD_LDS16(bgp  + (k0), &Bs[buf][wv * 512]);                        \
  } while (0)

  STAGE(0, 0);
  __syncthreads();

  const int a_off = (wr * 64 + (lane & 15)) * 32 + (lane >> 4) * 8;
  const int b_off = (wc * 32 + (lane & 15)) * 32 + (lane >> 4) * 8;

  for (int s = 0; s < nsteps; ++s) {
    const int nb = s & 1;
    if (s + 1 < nsteps) STAGE(nb ^ 1, (s + 1) * 32);

    const short* Ab = &As[nb][a_off];
    const short* Bb = &Bs[nb][b_off];
    short8 af0 = *reinterpret_cast<const short8*>(Ab);
    short8 af1 = *reinterpret_cast<const short8*>(Ab + 512);
    short8 af2 = *reinterpret_cast<const short8*>(Ab + 1024);
    short8 af3 = *reinterpret_cast<const short8*>(Ab + 1536);
    short8 bf0 = *reinterpret_cast<const short8*>(Bb);
    short8 bf1 = *reinterpret_cast<const short8*>(Bb + 512);

    acc[0][0] = __builtin_amdgcn_mfma_f32_16x16x32_bf16(af0, bf0, acc[0][0], 0, 0, 0);
    acc[0][1] = __builtin_amdgcn_mfma_f32_16x16x32_bf16(af0, bf1, acc[0][1], 0, 0, 0);
    acc[1][0] = __builtin_amdgcn_mfma_f32_16x16x32_bf16(af1, bf0, acc[1][0], 0, 0, 0);
    acc[1][1] = __builtin_amdgcn_mfma_f32_16x16x32_bf16(af1, bf1, acc[1][1], 0, 0, 0);
    acc[2][0] = __builtin_amdgcn_mfma_f32_16x16x32_bf16(af2, bf0, acc[2][0], 0, 0, 0);
    acc[2][1] = __builtin_amdgcn_mfma_f32_16x16x32_bf16(af2, bf1, acc[2][1], 0, 0, 0);
    acc[3][0] = __builtin_amdgcn_mfma_f32_16x16x32_bf16(af3, bf0, acc[3][0], 0, 0, 0);
    acc[3][1] = __builtin_amdgcn_mfma_f32_16x16x32_bf16(af3, bf1, acc[3][1], 0, 0, 0);

    __syncthreads();
  }
#undef STAGE

  // ---- epilogue: C/D map col=lane&15, row=4*(lane>>4)+reg ----
  const int cl = lane & 15, rh = lane >> 4;
#pragma unroll
  for (int fm = 0; fm < 4; ++fm) {
#pragma unroll
    for (int fn = 0; fn < 2; ++fn) {
      int col = nbase + wc * 32 + fn * 16 + cl;
      float bv = BIAS ? bias[col] : 0.f;
      f32x4 v = acc[fm][fn];
#pragma unroll
      for (int r = 0; r < 4; ++r) {
        int m = mbase + wr * 64 + fm * 16 + rh * 4 + r;
        if (m < M) {
          int b = m / To, to = m % To;
          float x = v[r] + bv;
          if (RELU) x = fmaxf(x, 0.f);
          size_t oi = ((size_t)b * TP_ + t_off_out + to) * (size_t)ldout + col;
          if (OUT_BF16) ((unsigned short*)out)[oi] = f2bf(x);
          else          ((float*)out)[oi] = x;
        }
      }
    }
  }
}

// ---------------------------------------------------------------------------
// Normalize v2 in place (fp32), emit bf16 copy + row norms vn.
// ---------------------------------------------------------------------------
__global__ void v2_norm_vn_k(float* __restrict__ v2, const float* __restrict__ ms,
                             unsigned short* __restrict__ v2bf, float* __restrict__ vn) {
  int r = blockIdx.x, t = threadIdx.x;
  float* row = v2 + (size_t)r * DJ_;
  unsigned short* brow = v2bf + (size_t)r * DJ_;
  float ss = 0.f;
#pragma unroll
  for (int h = 0; h < 2; ++h) {
    int c4 = t + h * 64;
    float4 v = reinterpret_cast<float4*>(row)[c4];
    int c = c4 * 4;
    v.x = (v.x - ms[c+0]) * ms[DJ_+c+0];
    v.y = (v.y - ms[c+1]) * ms[DJ_+c+1];
    v.z = (v.z - ms[c+2]) * ms[DJ_+c+2];
    v.w = (v.w - ms[c+3]) * ms[DJ_+c+3];
    reinterpret_cast<float4*>(row)[c4] = v;
    ushort4_t h4 = { f2bf(v.x), f2bf(v.y), f2bf(v.z), f2bf(v.w) };
    reinterpret_cast<ushort4_t*>(brow)[c4] = h4;
    ss += v.x*v.x + v.y*v.y + v.z*v.z + v.w*v.w;
  }
#pragma unroll
  for (int o = 32; o; o >>= 1) ss += __shfl_down(ss, o, 64);
  if (t == 0) vn[r] = sqrtf(ss);
}

// words normalize -> fp32 (for gram) + bf16 (for attention GEMM)
__global__ void wnorm_k(const float* __restrict__ words, const float* __restrict__ ms,
                        float* __restrict__ wbn, unsigned short* __restrict__ wbnb) {
  int idx = blockIdx.x * 256 + threadIdx.x;
  if (idx >= (B_ * L_ * DJ_) / 4) return;
  int c = (idx & 127) * 4;
  float4 v = reinterpret_cast<const float4*>(words)[idx];
  v.x = (v.x - ms[c+0]) * ms[DJ_+c+0];
  v.y = (v.y - ms[c+1]) * ms[DJ_+c+1];
  v.z = (v.z - ms[c+2]) * ms[DJ_+c+2];
  v.w = (v.w - ms[c+3]) * ms[DJ_+c+3];
  reinterpret_cast<float4*>(wbn)[idx] = v;
  ushort4_t h = { f2bf(v.x), f2bf(v.y), f2bf(v.z), f2bf(v.w) };
  reinterpret_cast<ushort4_t*>(wbnb)[idx] = h;
}

// Per-sentence Gram matrices G[i][l][l'] = w_l . w_l'
__global__ void gram_k(const float* __restrict__ wbn, float* __restrict__ G) {
  __shared__ float sw[L_ * 516];
  int i = blockIdx.x, tid = threadIdx.x;
  for (int idx = tid; idx < L_ * DJ_; idx += 256) {
    int l = idx >> 9, d = idx & 511;
    sw[l * 516 + d] = wbn[(size_t)i * L_ * DJ_ + idx];
  }
  __syncthreads();
  for (int p = tid; p < L_ * L_; p += 256) {
    int l = p / L_, l2 = p % L_;
    const float4* a = reinterpret_cast<const float4*>(&sw[l * 516]);
    const float4* b = reinterpret_cast<const float4*>(&sw[l2 * 516]);
    float acc = 0.f;
    for (int d4 = 0; d4 < 128; ++d4) {
      float4 av = a[d4], bv = b[d4];
      acc += av.x*bv.x + av.y*bv.y + av.z*bv.z + av.w*bv.w;
    }
    G[i * 400 + p] = acc;
  }
}

// ---------------------------------------------------------------------------
// sim kernel (unchanged from R1 — verified correct)
// ---------------------------------------------------------------------------
__global__ __launch_bounds__(256) void sim_k(
    const float* __restrict__ A, const float* __restrict__ G,
    const float* __restrict__ vn, const float* __restrict__ wmask,
    float* __restrict__ pos, float* __restrict__ scores) {
  int j = blockIdx.x, i = blockIdx.y;
  __shared__ float sG[400];
  __shared__ float sm[20];
  __shared__ float red[4];
  int tid = threadIdx.x;
  for (int p = tid; p < 400; p += 256) sG[p] = G[i * 400 + p];
  if (tid < 20) sm[tid] = wmask[i * 20 + tid];
  __syncthreads();

  float simv = -1e30f;
  if (tid < TP_) {
    const float* ar = A + ((size_t)j * TP_ + tid) * 640 + i * 20;
    float a[20], p[20];
    float mx = -1e30f;
#pragma unroll
    for (int l = 0; l < 20; ++l) {
      a[l] = ar[l];
      float lg = (sm[l] > 0.5f) ? LAM_ * a[l] : -1e9f;
      p[l] = lg;
      mx = fmaxf(mx, lg);
    }
    float Z = 0.f;
#pragma unroll
    for (int l = 0; l < 20; ++l) { p[l] = __expf(p[l] - mx); Z += p[l]; }
    float invZ = 1.f / Z, num = 0.f;
#pragma unroll
    for (int l = 0; l < 20; ++l) { p[l] *= invZ; num += p[l] * a[l]; }
    float q2 = 0.f;
#pragma unroll
    for (int l = 0; l < 20; ++l) {
      float gi = 0.f;
#pragma unroll
      for (int l2 = 0; l2 < 20; ++l2) gi += sG[l * 20 + l2] * p[l2];
      q2 += p[l] * gi;
    }
    float vnv = fmaxf(vn[(size_t)j * TP_ + tid], 1e-8f);
    float vsnv = fmaxf(sqrtf(q2), 1e-8f);
    simv = num / (vnv * vsnv);
    if (i == j) pos[i * TP_ + tid] = simv;
  }
  float mv = simv;
#pragma unroll
  for (int o = 32; o; o >>= 1) mv = fmaxf(mv, __shfl_down(mv, o, 64));
  if ((tid & 63) == 0) red[tid >> 6] = mv;
  __syncthreads();
  if (tid == 0)
    scores[i * 32 + j] = fmaxf(fmaxf(red[0], red[1]), fmaxf(red[2], red[3]));
}

// margin ranking loss over scores[32][32]
__global__ void loss_k(const float* __restrict__ scores, float* __restrict__ out) {
  __shared__ float red[16];
  int tid = threadIdx.x;
  int i = tid >> 5, j = tid & 31;
  float s = scores[tid];
  float dgi = scores[i * 32 + i], dgj = scores[j * 32 + j];
  float c = 0.f;
  if (i != j)
    c = fmaxf(0.f, MARGIN_ + s - dgi) + fmaxf(0.f, MARGIN_ + s - dgj);
#pragma unroll
  for (int o = 32; o; o >>= 1) c += __shfl_down(c, o, 64);
  if ((tid & 63) == 0) red[tid >> 6] = c;
  __syncthreads();
  if (tid == 0) {
    float t = 0.f;
    for (int w = 0; w < 16; ++w) t += red[w];
    out[0] = t / 32.f;
  }
}

// ---------------------------------------------------------------------------
extern "C" void kernel_launch(void* const* d_in, const int* in_sizes, int n_in,
                              void* d_out, int out_size, void* d_ws, size_t ws_size,
                              hipStream_t stream) {
  const float* video = (const float*)d_in[0];
  const float* words = (const float*)d_in[1];
  const float* wmask = (const float*)d_in[2];
  const float* c0w = (const float*)d_in[3];
  const float* c0b = (const float*)d_in[4];
  const float* c1w = (const float*)d_in[5];
  const float* c1b = (const float*)d_in[6];
  const float* c2w = (const float*)d_in[7];
  const float* c2b = (const float*)d_in[8];
  const float* pww = (const float*)d_in[9];
  const float* pwb = (const float*)d_in[10];
  float* out = (float*)d_out;
  float* ws  = (float*)d_ws;

  // workspace layout (float units).  Amat overlays vbf (both 4.19/4.49M; vbf
  // is dead after conv0, Amat written much later)  => total ~58 MB.
  float*          W0r    = ws;                                  // bf16 2097152 -> 1048576 f
  float*          W1r    = W0r + 1048576;                       // bf16 1048576 -> 524288 f
  float*          W2r    = W1r + 524288;                        // 524288 f
  float*          Wpw    = W2r + 524288;                        // bf16 262144 -> 131072 f (pad)
  float*          AMvbf  = Wpw + 131072;                        // max(vbf 4194304, Amat 4485120)
  float*          vcatb  = AMvbf + 4485120;                     // bf16 3588096 -> 1794048 f
  float*          v2     = vcatb + 1794048;                     // 3588096 f
  float*          v2bfp  = v2 + 3588096;                        // bf16 3588096 -> 1794048 f
  float*          wbn    = v2bfp + 1794048;                     // 327680 f
  float*          wbnbp  = wbn + 327680;                        // bf16 327680 -> 163840 f
  float*          G      = wbnbp + 163840;                      // 12800
  float*          vn     = G + 12800;                           // 7008
  float*          scores = vn + 7008;                           // 1024 (pad)
  float*          vpart  = scores + 1024;                       // 64*2048
  float*          vms    = vpart + 131072;                      // 2048
  float*          v2part = vms + 2048;                          // 64*1024
  float*          v2ms   = v2part + 65536;                      // 1024
  float*          wpart  = v2ms + 1024;                         // 16*1024
  float*          wms    = wpart + 16384;                       // 1024

  unsigned short* W0     = (unsigned short*)W0r;
  unsigned short* W1     = (unsigned short*)W1r;
  unsigned short* W2     = (unsigned short*)W2r;
  unsigned short* Wp     = (unsigned short*)Wpw;
  unsigned short* vbf    = (unsigned short*)AMvbf;
  float*          Amat   = AMvbf;
  unsigned short* vcb    = (unsigned short*)vcatb;
  unsigned short* v2bf   = (unsigned short*)v2bfp;
  unsigned short* wbnb   = (unsigned short*)wbnbp;

  // weight reorder + bf16 cast
  reorder_w_bf_k<<<(2097152 + 255) / 256, 256, 0, stream>>>(c0w, W0, 1024, 4, 2097152);
  reorder_w_bf_k<<<(1048576 + 255) / 256, 256, 0, stream>>>(c1w, W1, 512, 4, 1048576);
  reorder_w_bf_k<<<(1048576 + 255) / 256, 256, 0, stream>>>(c2w, W2, 512, 4, 1048576);
  reorder_w_bf_k<<<(262144 + 255) / 256, 256, 0, stream>>>(pww, Wp, 512, 1, 262144);

  // video BN stats + apply/cast
  stats_partial_k<<<64, 256, 0, stream>>>(video, vpart, 1024, 8192, 128);
  stats_final_k<<<4, 256, 0, stream>>>(vpart, vms, 1024, 64, 1.f / 8192.f);
  vid_bn_cast_k<<<8192, 256, 0, stream>>>(video, vms, vbf);

  // conv tower (bf16 MFMA GEMMs) -> vcat bf16
  mfma_gemm_k<true, true, true><<<dim3(32, 8), 256, 0, stream>>>(
      vbf, W0, c0b, vcb, 262144, 0, 2048, T0_, 32 * T0_, 0, 512, 4096);
  mfma_gemm_k<true, true, true><<<dim3(16, 8), 256, 0, stream>>>(
      vcb, W1, c1b, vcb, 112128, 0, 1024, T1_, 32 * T1_, T0_, 512, 2048);
  mfma_gemm_k<true, true, true><<<dim3(8, 8), 256, 0, stream>>>(
      vcb, W2, c2b, vcb, 112128, 65024, 1024, T2_, 32 * T2_, T0_ + T1_, 512, 2048);
  // pointwise conv -> v2 fp32
  mfma_gemm_k<false, true, false><<<dim3(55, 8), 256, 0, stream>>>(
      vcb, Wp, pwb, v2, 112128, 0, 512, TP_, 32 * TP_, 0, 512, 512);

  // v2 BN (+ bf16 copy + row norms)
  stats_partial_k<<<64, 128, 0, stream>>>(v2, v2part, 512, 7008, 110);
  stats_final_k<<<2, 256, 0, stream>>>(v2part, v2ms, 512, 64, 1.f / 7008.f);
  v2_norm_vn_k<<<7008, 64, 0, stream>>>(v2, v2ms, v2bf, vn);

  // words BN
  stats_partial_k<<<16, 128, 0, stream>>>(words, wpart, 512, 640, 40);
  stats_final_k<<<2, 256, 0, stream>>>(wpart, wms, 512, 16, 1.f / 640.f);
  wnorm_k<<<(81920 + 255) / 256, 256, 0, stream>>>(words, wms, wbn, wbnb);
  gram_k<<<32, 256, 0, stream>>>(wbn, G);

  // A[(j,t)][(i,l)] = v . w  (M=7008, N=640, K=512) -> Amat fp32 (overlays vbf)
  mfma_gemm_k<false, false, false><<<dim3(55, 10), 256, 0, stream>>>(
      v2bf, wbnb, nullptr, Amat, 112128, 0, 512, TP_, 32 * TP_, 0, 640, 512);

  // fused softmax / cosine-sim / scores / positive_map
  sim_k<<<dim3(32, 32), 256, 0, stream>>>(Amat, G, vn, wmask, out + 1, scores);
  loss_k<<<1, 1024, 0, stream>>>(scores, out);
}

// Round 3
// 316.505 us; speedup vs baseline: 2.6434x; 1.1167x over previous
//
#include <hip/hip_runtime.h>
#include <math.h>

// Problem constants
#define B_   32
#define T_   256
#define DV_  1024
#define DJ_  512
#define L_   20
#define T0_  127
#define T1_  62
#define T2_  30
#define TP_  219          // 127+62+30
#define LAM_ 4.0f
#define MARGIN_ 0.1f

typedef __attribute__((ext_vector_type(8))) short short8;
typedef __attribute__((ext_vector_type(4))) float f32x4;

static __device__ __forceinline__ unsigned short f2bf(float f) {
  union { float f; unsigned u; } v; v.f = f;
  unsigned r = v.u + 0x7fff + ((v.u >> 16) & 1);   // round-to-nearest-even
  return (unsigned short)(r >> 16);
}

struct ushort4_t { unsigned short x, y, z, w; };

#define GLOAD_LDS16(gp, lp)                                                      \
  __builtin_amdgcn_global_load_lds(                                              \
      (const __attribute__((address_space(1))) void*)(gp),                       \
      (__attribute__((address_space(3))) void*)(lp), 16, 0, 0)

// ---------------------------------------------------------------------------
// All weight reorders+casts in one launch: [co][ci][k] -> bf16 [co][k*Cin+ci]
// ---------------------------------------------------------------------------
__global__ void reorder_all_k(const float* __restrict__ c0w, const float* __restrict__ c1w,
                              const float* __restrict__ c2w, const float* __restrict__ pww,
                              unsigned short* __restrict__ W0, unsigned short* __restrict__ W1,
                              unsigned short* __restrict__ W2, unsigned short* __restrict__ Wp) {
  int idx = blockIdx.x * 256 + threadIdx.x;
  const float* src; unsigned short* dst; int Cin, KS, local;
  if (idx < 2097152)      { src = c0w; dst = W0; Cin = 1024; KS = 4; local = idx; }
  else if (idx < 3145728) { src = c1w; dst = W1; Cin = 512;  KS = 4; local = idx - 2097152; }
  else if (idx < 4194304) { src = c2w; dst = W2; Cin = 512;  KS = 4; local = idx - 3145728; }
  else if (idx < 4456448) { src = pww; dst = Wp; Cin = 512;  KS = 1; local = idx - 4194304; }
  else return;
  int KC = Cin * KS;
  int co = local / KC, rem = local % KC;
  int k = rem / Cin, ci = rem % Cin;
  dst[local] = f2bf(src[(co * Cin + ci) * KS + k]);
}

// ---------------------------------------------------------------------------
// BatchNorm stats, two stage (deterministic, no atomics).
// ---------------------------------------------------------------------------
__global__ void stats_partial_k(const float* __restrict__ x, float* __restrict__ part,
                                int C, int rows, int rpg) {
  int rg = blockIdx.x, t = threadIdx.x;
  int r0 = rg * rpg, r1 = min(r0 + rpg, rows);
  float4 s = {0.f,0.f,0.f,0.f}, q = {0.f,0.f,0.f,0.f};
  for (int r = r0; r < r1; ++r) {
    float4 v = *reinterpret_cast<const float4*>(&x[(size_t)r * C + t * 4]);
    s.x += v.x; s.y += v.y; s.z += v.z; s.w += v.w;
    q.x += v.x*v.x; q.y += v.y*v.y; q.z += v.z*v.z; q.w += v.w*v.w;
  }
  float* ps = part + (size_t)rg * 2 * C;
  reinterpret_cast<float4*>(ps)[t] = s;
  reinterpret_cast<float4*>(ps + C)[t] = q;
}

__global__ void stats_final_k(const float* __restrict__ part, float* __restrict__ ms,
                              int C, int ng, float inv_n) {
  int c = blockIdx.x * 256 + threadIdx.x;
  if (c >= C) return;
  float s = 0.f, q = 0.f;
  for (int g = 0; g < ng; ++g) {
    s += part[(size_t)g * 2 * C + c];
    q += part[(size_t)g * 2 * C + C + c];
  }
  float m = s * inv_n;
  float var = q * inv_n - m * m;
  ms[c] = m;
  ms[C + c] = rsqrtf(var + 1e-5f);
}

// video BN apply + cast to bf16
__global__ void vid_bn_cast_k(const float* __restrict__ video,
                              const float* __restrict__ ms,
                              unsigned short* __restrict__ vbf) {
  int i4 = blockIdx.x * 256 + threadIdx.x;
  float4 v = reinterpret_cast<const float4*>(video)[i4];
  int c = (i4 & 255) * 4;
  v.x = (v.x - ms[c+0]) * ms[1024+c+0];
  v.y = (v.y - ms[c+1]) * ms[1024+c+1];
  v.z = (v.z - ms[c+2]) * ms[1024+c+2];
  v.w = (v.w - ms[c+3]) * ms[1024+c+3];
  ushort4_t h = { f2bf(v.x), f2bf(v.y), f2bf(v.z), f2bf(v.w) };
  reinterpret_cast<ushort4_t*>(vbf)[i4] = h;
}

// ---------------------------------------------------------------------------
// MFMA bf16 GEMM.  BM=64, BN=64, BK=32, 256 thr = 4 waves (2x2), wave tile
// 32x32 (2x2 frags of 16x16x32).  LDS linear + source-side chunk swizzle
// chunk ^= (row ^ row>>2) & 3  (same involution applied on the read side)
// -> 2-way max bank aliasing on ds_read_b128 (free).
// ---------------------------------------------------------------------------
template<bool RELU, bool BIAS, bool OUT_BF16>
__global__ __launch_bounds__(256) void mfma_gemm_k(
    const unsigned short* __restrict__ xin, const unsigned short* __restrict__ Wr,
    const float* __restrict__ bias, void* __restrict__ out,
    int b_stride, int row_off, int row_t_stride,
    int To, int M, int t_off_out, int ldout, int Ktot)
{
  __shared__ __align__(16) short As[2][64 * 32];
  __shared__ __align__(16) short Bs[2][64 * 32];

  const int tid  = threadIdx.x;
  const int lane = tid & 63;
  const int wv   = tid >> 6;       // wave 0..3
  const int wr   = wv >> 1;        // wave row (M)
  const int wc   = wv & 1;         // wave col (N)
  const int mbase = blockIdx.x * 64;
  const int nbase = blockIdx.y * 64;

  // ---- staging: thread -> (tile row, 16B chunk); source chunk pre-swizzled
  const int srow = tid >> 2;                       // 0..63
  const int sb   = (((tid & 3) ^ ((srow ^ (srow >> 2)) & 3))) * 8;
  int ma = min(mbase + srow, M - 1);
  int b0 = ma / To, t0 = ma % To;
  const unsigned short* agp = xin + (size_t)b0 * b_stride + row_off
                              + (size_t)t0 * row_t_stride + sb;
  const unsigned short* bgp = Wr + (size_t)(nbase + srow) * Ktot + sb;

  f32x4 acc[2][2] = {};
  const int nsteps = Ktot >> 5;

#define STAGE(buf, k0)                                        \
  do {                                                        \
    GLOAD_LDS16(agp + (k0), &As[buf][wv * 512]);              \
    GLOAD_LDS16(bgp + (k0), &Bs[buf][wv * 512]);              \
  } while (0)

  STAGE(0, 0);
  __syncthreads();

  // ---- read offsets (same swizzle involution) ----
  const int rsw   = (lane ^ (lane >> 2)) & 3;
  const int chunk = ((lane >> 4) ^ rsw) * 8;
  const int a_off = (wr * 32 + (lane & 15)) * 32 + chunk;
  const int b_off = (wc * 32 + (lane & 15)) * 32 + chunk;

  for (int s = 0; s < nsteps; ++s) {
    const int nb = s & 1;
    if (s + 1 < nsteps) STAGE(nb ^ 1, (s + 1) * 32);

    const short* Ab = &As[nb][a_off];
    const short* Bb = &Bs[nb][b_off];
    short8 af0 = *reinterpret_cast<const short8*>(Ab);
    short8 af1 = *reinterpret_cast<const short8*>(Ab + 512);
    short8 bf0 = *reinterpret_cast<const short8*>(Bb);
    short8 bf1 = *reinterpret_cast<const short8*>(Bb + 512);

    acc[0][0] = __builtin_amdgcn_mfma_f32_16x16x32_bf16(af0, bf0, acc[0][0], 0, 0, 0);
    acc[0][1] = __builtin_amdgcn_mfma_f32_16x16x32_bf16(af0, bf1, acc[0][1], 0, 0, 0);
    acc[1][0] = __builtin_amdgcn_mfma_f32_16x16x32_bf16(af1, bf0, acc[1][0], 0, 0, 0);
    acc[1][1] = __builtin_amdgcn_mfma_f32_16x16x32_bf16(af1, bf1, acc[1][1], 0, 0, 0);

    __syncthreads();
  }
#undef STAGE

  // ---- epilogue: C/D map col=lane&15, row=4*(lane>>4)+reg ----
  const int cl = lane & 15, rh = lane >> 4;
#pragma unroll
  for (int fm = 0; fm < 2; ++fm) {
#pragma unroll
    for (int fn = 0; fn < 2; ++fn) {
      int col = nbase + wc * 32 + fn * 16 + cl;
      float bv = BIAS ? bias[col] : 0.f;
      f32x4 v = acc[fm][fn];
#pragma unroll
      for (int r = 0; r < 4; ++r) {
        int m = mbase + wr * 32 + fm * 16 + rh * 4 + r;
        if (m < M) {
          int b = m / To, to = m % To;
          float x = v[r] + bv;
          if (RELU) x = fmaxf(x, 0.f);
          size_t oi = ((size_t)b * TP_ + t_off_out + to) * (size_t)ldout + col;
          if (OUT_BF16) ((unsigned short*)out)[oi] = f2bf(x);
          else          ((float*)out)[oi] = x;
        }
      }
    }
  }
}

// ---------------------------------------------------------------------------
// Normalize v2 in place (fp32), emit bf16 copy + row norms vn.
// ---------------------------------------------------------------------------
__global__ void v2_norm_vn_k(float* __restrict__ v2, const float* __restrict__ ms,
                             unsigned short* __restrict__ v2bf, float* __restrict__ vn) {
  int r = blockIdx.x, t = threadIdx.x;
  float* row = v2 + (size_t)r * DJ_;
  unsigned short* brow = v2bf + (size_t)r * DJ_;
  float ss = 0.f;
#pragma unroll
  for (int h = 0; h < 2; ++h) {
    int c4 = t + h * 64;
    float4 v = reinterpret_cast<float4*>(row)[c4];
    int c = c4 * 4;
    v.x = (v.x - ms[c+0]) * ms[DJ_+c+0];
    v.y = (v.y - ms[c+1]) * ms[DJ_+c+1];
    v.z = (v.z - ms[c+2]) * ms[DJ_+c+2];
    v.w = (v.w - ms[c+3]) * ms[DJ_+c+3];
    reinterpret_cast<float4*>(row)[c4] = v;
    ushort4_t h4 = { f2bf(v.x), f2bf(v.y), f2bf(v.z), f2bf(v.w) };
    reinterpret_cast<ushort4_t*>(brow)[c4] = h4;
    ss += v.x*v.x + v.y*v.y + v.z*v.z + v.w*v.w;
  }
#pragma unroll
  for (int o = 32; o; o >>= 1) ss += __shfl_down(ss, o, 64);
  if (t == 0) vn[r] = sqrtf(ss);
}

// words normalize -> fp32 (for gram) + bf16 (for attention GEMM)
__global__ void wnorm_k(const float* __restrict__ words, const float* __restrict__ ms,
                        float* __restrict__ wbn, unsigned short* __restrict__ wbnb) {
  int idx = blockIdx.x * 256 + threadIdx.x;
  if (idx >= (B_ * L_ * DJ_) / 4) return;
  int c = (idx & 127) * 4;
  float4 v = reinterpret_cast<const float4*>(words)[idx];
  v.x = (v.x - ms[c+0]) * ms[DJ_+c+0];
  v.y = (v.y - ms[c+1]) * ms[DJ_+c+1];
  v.z = (v.z - ms[c+2]) * ms[DJ_+c+2];
  v.w = (v.w - ms[c+3]) * ms[DJ_+c+3];
  reinterpret_cast<float4*>(wbn)[idx] = v;
  ushort4_t h = { f2bf(v.x), f2bf(v.y), f2bf(v.z), f2bf(v.w) };
  reinterpret_cast<ushort4_t*>(wbnb)[idx] = h;
}

// Per-sentence Gram matrices G[i][l][l'] = w_l . w_l'
__global__ void gram_k(const float* __restrict__ wbn, float* __restrict__ G) {
  __shared__ float sw[L_ * 516];
  int i = blockIdx.x, tid = threadIdx.x;
  for (int idx = tid; idx < L_ * DJ_; idx += 256) {
    int l = idx >> 9, d = idx & 511;
    sw[l * 516 + d] = wbn[(size_t)i * L_ * DJ_ + idx];
  }
  __syncthreads();
  for (int p = tid; p < L_ * L_; p += 256) {
    int l = p / L_, l2 = p % L_;
    const float4* a = reinterpret_cast<const float4*>(&sw[l * 516]);
    const float4* b = reinterpret_cast<const float4*>(&sw[l2 * 516]);
    float acc = 0.f;
    for (int d4 = 0; d4 < 128; ++d4) {
      float4 av = a[d4], bv = b[d4];
      acc += av.x*bv.x + av.y*bv.y + av.z*bv.z + av.w*bv.w;
    }
    G[i * 400 + p] = acc;
  }
}

// ---------------------------------------------------------------------------
// sim kernel
// ---------------------------------------------------------------------------
__global__ __launch_bounds__(256) void sim_k(
    const float* __restrict__ A, const float* __restrict__ G,
    const float* __restrict__ vn, const float* __restrict__ wmask,
    float* __restrict__ pos, float* __restrict__ scores) {
  int j = blockIdx.x, i = blockIdx.y;
  __shared__ float sG[400];
  __shared__ float sm[20];
  __shared__ float red[4];
  int tid = threadIdx.x;
  for (int p = tid; p < 400; p += 256) sG[p] = G[i * 400 + p];
  if (tid < 20) sm[tid] = wmask[i * 20 + tid];
  __syncthreads();

  float simv = -1e30f;
  if (tid < TP_) {
    const float* ar = A + ((size_t)j * TP_ + tid) * 640 + i * 20;
    float a[20], p[20];
    float mx = -1e30f;
#pragma unroll
    for (int l = 0; l < 20; ++l) {
      a[l] = ar[l];
      float lg = (sm[l] > 0.5f) ? LAM_ * a[l] : -1e9f;
      p[l] = lg;
      mx = fmaxf(mx, lg);
    }
    float Z = 0.f;
#pragma unroll
    for (int l = 0; l < 20; ++l) { p[l] = __expf(p[l] - mx); Z += p[l]; }
    float invZ = 1.f / Z, num = 0.f;
#pragma unroll
    for (int l = 0; l < 20; ++l) { p[l] *= invZ; num += p[l] * a[l]; }
    float q2 = 0.f;
#pragma unroll
    for (int l = 0; l < 20; ++l) {
      float gi = 0.f;
#pragma unroll
      for (int l2 = 0; l2 < 20; ++l2) gi += sG[l * 20 + l2] * p[l2];
      q2 += p[l] * gi;
    }
    float vnv = fmaxf(vn[(size_t)j * TP_ + tid], 1e-8f);
    float vsnv = fmaxf(sqrtf(q2), 1e-8f);
    simv = num / (vnv * vsnv);
    if (i == j) pos[i * TP_ + tid] = simv;
  }
  float mv = simv;
#pragma unroll
  for (int o = 32; o; o >>= 1) mv = fmaxf(mv, __shfl_down(mv, o, 64));
  if ((tid & 63) == 0) red[tid >> 6] = mv;
  __syncthreads();
  if (tid == 0)
    scores[i * 32 + j] = fmaxf(fmaxf(red[0], red[1]), fmaxf(red[2], red[3]));
}

// margin ranking loss over scores[32][32]
__global__ void loss_k(const float* __restrict__ scores, float* __restrict__ out) {
  __shared__ float red[16];
  int tid = threadIdx.x;
  int i = tid >> 5, j = tid & 31;
  float s = scores[tid];
  float dgi = scores[i * 32 + i], dgj = scores[j * 32 + j];
  float c = 0.f;
  if (i != j)
    c = fmaxf(0.f, MARGIN_ + s - dgi) + fmaxf(0.f, MARGIN_ + s - dgj);
#pragma unroll
  for (int o = 32; o; o >>= 1) c += __shfl_down(c, o, 64);
  if ((tid & 63) == 0) red[tid >> 6] = c;
  __syncthreads();
  if (tid == 0) {
    float t = 0.f;
    for (int w = 0; w < 16; ++w) t += red[w];
    out[0] = t / 32.f;
  }
}

// ---------------------------------------------------------------------------
extern "C" void kernel_launch(void* const* d_in, const int* in_sizes, int n_in,
                              void* d_out, int out_size, void* d_ws, size_t ws_size,
                              hipStream_t stream) {
  const float* video = (const float*)d_in[0];
  const float* words = (const float*)d_in[1];
  const float* wmask = (const float*)d_in[2];
  const float* c0w = (const float*)d_in[3];
  const float* c0b = (const float*)d_in[4];
  const float* c1w = (const float*)d_in[5];
  const float* c1b = (const float*)d_in[6];
  const float* c2w = (const float*)d_in[7];
  const float* c2b = (const float*)d_in[8];
  const float* pww = (const float*)d_in[9];
  const float* pwb = (const float*)d_in[10];
  float* out = (float*)d_out;
  float* ws  = (float*)d_ws;

  // workspace layout (float units).  Amat overlays vbf.
  float*          W0r    = ws;                                  // bf16 2097152 -> 1048576 f
  float*          W1r    = W0r + 1048576;                       // bf16 1048576 -> 524288 f
  float*          W2r    = W1r + 524288;                        // 524288 f
  float*          Wpw    = W2r + 524288;                        // bf16 262144 -> 131072 f
  float*          AMvbf  = Wpw + 131072;                        // max(vbf, Amat) = 4485120 f
  float*          vcatb  = AMvbf + 4485120;                     // bf16 3588096 -> 1794048 f
  float*          v2     = vcatb + 1794048;                     // 3588096 f
  float*          v2bfp  = v2 + 3588096;                        // bf16 -> 1794048 f
  float*          wbn    = v2bfp + 1794048;                     // 327680 f
  float*          wbnbp  = wbn + 327680;                        // bf16 -> 163840 f
  float*          G      = wbnbp + 163840;                      // 12800
  float*          vn     = G + 12800;                           // 7008
  float*          scores = vn + 7008;                           // 1024
  float*          vpart  = scores + 1024;                       // 64*2048
  float*          vms    = vpart + 131072;                      // 2048
  float*          v2part = vms + 2048;                          // 64*1024
  float*          v2ms   = v2part + 65536;                      // 1024
  float*          wpart  = v2ms + 1024;                         // 16*1024
  float*          wms    = wpart + 16384;                       // 1024

  unsigned short* W0     = (unsigned short*)W0r;
  unsigned short* W1     = (unsigned short*)W1r;
  unsigned short* W2     = (unsigned short*)W2r;
  unsigned short* Wp     = (unsigned short*)Wpw;
  unsigned short* vbf    = (unsigned short*)AMvbf;
  float*          Amat   = AMvbf;
  unsigned short* vcb    = (unsigned short*)vcatb;
  unsigned short* v2bf   = (unsigned short*)v2bfp;
  unsigned short* wbnb   = (unsigned short*)wbnbp;

  // weight reorder + bf16 cast (single launch)
  reorder_all_k<<<17408, 256, 0, stream>>>(c0w, c1w, c2w, pww, W0, W1, W2, Wp);

  // video BN stats + apply/cast
  stats_partial_k<<<64, 256, 0, stream>>>(video, vpart, 1024, 8192, 128);
  stats_final_k<<<4, 256, 0, stream>>>(vpart, vms, 1024, 64, 1.f / 8192.f);
  vid_bn_cast_k<<<8192, 256, 0, stream>>>(video, vms, vbf);

  // conv tower (bf16 MFMA GEMMs) -> vcat bf16
  mfma_gemm_k<true, true, true><<<dim3(64, 8), 256, 0, stream>>>(
      vbf, W0, c0b, vcb, 262144, 0, 2048, T0_, 32 * T0_, 0, 512, 4096);
  mfma_gemm_k<true, true, true><<<dim3(31, 8), 256, 0, stream>>>(
      vcb, W1, c1b, vcb, 112128, 0, 1024, T1_, 32 * T1_, T0_, 512, 2048);
  mfma_gemm_k<true, true, true><<<dim3(15, 8), 256, 0, stream>>>(
      vcb, W2, c2b, vcb, 112128, 65024, 1024, T2_, 32 * T2_, T0_ + T1_, 512, 2048);
  // pointwise conv -> v2 fp32
  mfma_gemm_k<false, true, false><<<dim3(110, 8), 256, 0, stream>>>(
      vcb, Wp, pwb, v2, 112128, 0, 512, TP_, 32 * TP_, 0, 512, 512);

  // v2 BN (+ bf16 copy + row norms)
  stats_partial_k<<<64, 128, 0, stream>>>(v2, v2part, 512, 7008, 110);
  stats_final_k<<<2, 256, 0, stream>>>(v2part, v2ms, 512, 64, 1.f / 7008.f);
  v2_norm_vn_k<<<7008, 64, 0, stream>>>(v2, v2ms, v2bf, vn);

  // words BN
  stats_partial_k<<<16, 128, 0, stream>>>(words, wpart, 512, 640, 40);
  stats_final_k<<<2, 256, 0, stream>>>(wpart, wms, 512, 16, 1.f / 640.f);
  wnorm_k<<<(81920 + 255) / 256, 256, 0, stream>>>(words, wms, wbn, wbnb);
  gram_k<<<32, 256, 0, stream>>>(wbn, G);

  // A[(j,t)][(i,l)] = v . w  (M=7008, N=640, K=512) -> Amat fp32 (overlays vbf)
  mfma_gemm_k<false, false, false><<<dim3(110, 10), 256, 0, stream>>>(
      v2bf, wbnb, nullptr, Amat, 112128, 0, 512, TP_, 32 * TP_, 0, 640, 512);

  // fused softmax / cosine-sim / scores / positive_map
  sim_k<<<dim3(32, 32), 256, 0, stream>>>(Amat, G, vn, wmask, out + 1, scores);
  loss_k<<<1, 1024, 0, stream>>>(scores, out);
}

// Round 4
// 270.938 us; speedup vs baseline: 3.0879x; 1.1682x over previous
//
#include <hip/hip_runtime.h>
#include <math.h>

// Problem constants
#define B_   32
#define T_   256
#define DV_  1024
#define DJ_  512
#define L_   20
#define T0_  127
#define T1_  62
#define T2_  30
#define TP_  219          // 127+62+30
#define LAM_ 4.0f
#define MARGIN_ 0.1f

typedef __attribute__((ext_vector_type(8))) short short8;
typedef __attribute__((ext_vector_type(4))) float f32x4;

static __device__ __forceinline__ unsigned short f2bf(float f) {
  union { float f; unsigned u; } v; v.f = f;
  unsigned r = v.u + 0x7fff + ((v.u >> 16) & 1);   // round-to-nearest-even
  return (unsigned short)(r >> 16);
}

struct ushort4_t { unsigned short x, y, z, w; };

#define GLOAD_LDS16(gp, lp)                                                      \
  __builtin_amdgcn_global_load_lds(                                              \
      (const __attribute__((address_space(1))) void*)(gp),                       \
      (__attribute__((address_space(3))) void*)(lp), 16, 0, 0)

// ---------------------------------------------------------------------------
// Weight reorder+cast, coalesced: thread = (co,ci), float4 read of 4 taps,
// 4 coalesced ushort stores at stride Cin.  pw = straight cast.
// ---------------------------------------------------------------------------
__global__ void reorder_all_k(const float* __restrict__ c0w, const float* __restrict__ c1w,
                              const float* __restrict__ c2w, const float* __restrict__ pww,
                              unsigned short* __restrict__ W0, unsigned short* __restrict__ W1,
                              unsigned short* __restrict__ W2, unsigned short* __restrict__ Wp) {
  int bid = blockIdx.x;
  if (bid < 2048) {            // conv0: 512*1024 (co,ci) pairs
    int idx = bid * 256 + threadIdx.x;
    int co = idx >> 10, ci = idx & 1023;
    float4 w = *reinterpret_cast<const float4*>(c0w + (size_t)idx * 4);
    unsigned short* d = W0 + (size_t)co * 4096 + ci;
    d[0] = f2bf(w.x); d[1024] = f2bf(w.y); d[2048] = f2bf(w.z); d[3072] = f2bf(w.w);
  } else if (bid < 3072) {     // conv1: 512*512
    int idx = (bid - 2048) * 256 + threadIdx.x;
    int co = idx >> 9, ci = idx & 511;
    float4 w = *reinterpret_cast<const float4*>(c1w + (size_t)idx * 4);
    unsigned short* d = W1 + (size_t)co * 2048 + ci;
    d[0] = f2bf(w.x); d[512] = f2bf(w.y); d[1024] = f2bf(w.z); d[1536] = f2bf(w.w);
  } else if (bid < 4096) {     // conv2: 512*512
    int idx = (bid - 3072) * 256 + threadIdx.x;
    int co = idx >> 9, ci = idx & 511;
    float4 w = *reinterpret_cast<const float4*>(c2w + (size_t)idx * 4);
    unsigned short* d = W2 + (size_t)co * 2048 + ci;
    d[0] = f2bf(w.x); d[512] = f2bf(w.y); d[1024] = f2bf(w.z); d[1536] = f2bf(w.w);
  } else {                     // pw: identity cast, 262144 elems / 4
    int idx = (bid - 4096) * 256 + threadIdx.x;
    float4 v = *reinterpret_cast<const float4*>(pww + (size_t)idx * 4);
    ushort4_t h = { f2bf(v.x), f2bf(v.y), f2bf(v.z), f2bf(v.w) };
    reinterpret_cast<ushort4_t*>(Wp)[idx] = h;
  }
}

// ---------------------------------------------------------------------------
// BatchNorm stats, two stage, deterministic, highly parallel.
// Stage 1: block g covers rpg rows; thread = (rsub, c4); writes
// part[g*nsub+rsub][2C] (sums then sumsqs), float4-coalesced.
// ---------------------------------------------------------------------------
__global__ void stats1_k(const float* __restrict__ x, float* __restrict__ part,
                         int C, int rows, int rpg, int cpgShift) {
  int cpg  = 1 << cpgShift;                 // C/4
  int c4   = threadIdx.x & (cpg - 1);
  int rsub = threadIdx.x >> cpgShift;
  int nsub = 256 >> cpgShift;
  int r0 = blockIdx.x * rpg + rsub;
  int r1 = min(blockIdx.x * rpg + rpg, rows);
  float4 s = {0.f,0.f,0.f,0.f}, q = {0.f,0.f,0.f,0.f};
  for (int r = r0; r < r1; r += nsub) {
    float4 v = *reinterpret_cast<const float4*>(&x[(size_t)r * C + c4 * 4]);
    s.x += v.x; s.y += v.y; s.z += v.z; s.w += v.w;
    q.x += v.x*v.x; q.y += v.y*v.y; q.z += v.z*v.z; q.w += v.w*v.w;
  }
  float* ps = part + ((size_t)blockIdx.x * nsub + rsub) * 2 * C;
  reinterpret_cast<float4*>(ps)[c4] = s;
  reinterpret_cast<float4*>(ps + C)[c4] = q;
}

// Stage 2: block handles 128 channels (32 float4); 8 g-stripes; LDS combine.
__global__ void stats2_k(const float* __restrict__ part, float* __restrict__ ms,
                         int C, int ng, float inv_n) {
  __shared__ float4 sS[8][33], sQ[8][33];
  int c4l = threadIdx.x & 31;
  int gs  = threadIdx.x >> 5;
  int c4  = blockIdx.x * 32 + c4l;          // float4 channel index
  float4 s = {0.f,0.f,0.f,0.f}, q = {0.f,0.f,0.f,0.f};
  for (int g = gs; g < ng; g += 8) {
    const float4* ps = reinterpret_cast<const float4*>(part + (size_t)g * 2 * C);
    float4 a = ps[c4];
    float4 b = ps[(C >> 2) + c4];
    s.x += a.x; s.y += a.y; s.z += a.z; s.w += a.w;
    q.x += b.x; q.y += b.y; q.z += b.z; q.w += b.w;
  }
  sS[gs][c4l] = s; sQ[gs][c4l] = q;
  __syncthreads();
  if (gs == 0) {
    float4 S = sS[0][c4l], Q = sQ[0][c4l];
#pragma unroll
    for (int k = 1; k < 8; ++k) {
      float4 a = sS[k][c4l], b = sQ[k][c4l];
      S.x += a.x; S.y += a.y; S.z += a.z; S.w += a.w;
      Q.x += b.x; Q.y += b.y; Q.z += b.z; Q.w += b.w;
    }
    int c = c4 * 4;
    float m0 = S.x * inv_n, m1 = S.y * inv_n, m2 = S.z * inv_n, m3 = S.w * inv_n;
    ms[c+0] = m0; ms[C+c+0] = rsqrtf(Q.x * inv_n - m0*m0 + 1e-5f);
    ms[c+1] = m1; ms[C+c+1] = rsqrtf(Q.y * inv_n - m1*m1 + 1e-5f);
    ms[c+2] = m2; ms[C+c+2] = rsqrtf(Q.z * inv_n - m2*m2 + 1e-5f);
    ms[c+3] = m3; ms[C+c+3] = rsqrtf(Q.w * inv_n - m3*m3 + 1e-5f);
  }
}

// video BN apply + cast to bf16
__global__ void vid_bn_cast_k(const float* __restrict__ video,
                              const float* __restrict__ ms,
                              unsigned short* __restrict__ vbf) {
  int i4 = blockIdx.x * 256 + threadIdx.x;
  float4 v = reinterpret_cast<const float4*>(video)[i4];
  int c = (i4 & 255) * 4;
  v.x = (v.x - ms[c+0]) * ms[1024+c+0];
  v.y = (v.y - ms[c+1]) * ms[1024+c+1];
  v.z = (v.z - ms[c+2]) * ms[1024+c+2];
  v.w = (v.w - ms[c+3]) * ms[1024+c+3];
  ushort4_t h = { f2bf(v.x), f2bf(v.y), f2bf(v.z), f2bf(v.w) };
  reinterpret_cast<ushort4_t*>(vbf)[i4] = h;
}

// ---------------------------------------------------------------------------
// MFMA bf16 GEMM.  BM=64, BN=64, BK=32, 256 thr = 4 waves (2x2), wave tile
// 32x32 (2x2 frags of 16x16x32).  LDS linear + source-side chunk swizzle
// (same involution on read side) -> 2-way max bank aliasing (free).
// ---------------------------------------------------------------------------
template<bool RELU, bool BIAS, bool OUT_BF16>
__global__ __launch_bounds__(256) void mfma_gemm_k(
    const unsigned short* __restrict__ xin, const unsigned short* __restrict__ Wr,
    const float* __restrict__ bias, void* __restrict__ out,
    int b_stride, int row_off, int row_t_stride,
    int To, int M, int t_off_out, int ldout, int Ktot)
{
  __shared__ __align__(16) short As[2][64 * 32];
  __shared__ __align__(16) short Bs[2][64 * 32];

  const int tid  = threadIdx.x;
  const int lane = tid & 63;
  const int wv   = tid >> 6;
  const int wr   = wv >> 1;
  const int wc   = wv & 1;
  const int mbase = blockIdx.x * 64;
  const int nbase = blockIdx.y * 64;

  const int srow = tid >> 2;
  const int sb   = (((tid & 3) ^ ((srow ^ (srow >> 2)) & 3))) * 8;
  int ma = min(mbase + srow, M - 1);
  int b0 = ma / To, t0 = ma % To;
  const unsigned short* agp = xin + (size_t)b0 * b_stride + row_off
                              + (size_t)t0 * row_t_stride + sb;
  const unsigned short* bgp = Wr + (size_t)(nbase + srow) * Ktot + sb;

  f32x4 acc[2][2] = {};
  const int nsteps = Ktot >> 5;

#define STAGE(buf, k0)                                        \
  do {                                                        \
    GLOAD_LDS16(agp + (k0), &As[buf][wv * 512]);              \
    GLOAD_LDS16(bgp + (k0), &Bs[buf][wv * 512]);              \
  } while (0)

  STAGE(0, 0);
  __syncthreads();

  const int rsw   = (lane ^ (lane >> 2)) & 3;
  const int chunk = ((lane >> 4) ^ rsw) * 8;
  const int a_off = (wr * 32 + (lane & 15)) * 32 + chunk;
  const int b_off = (wc * 32 + (lane & 15)) * 32 + chunk;

  for (int s = 0; s < nsteps; ++s) {
    const int nb = s & 1;
    if (s + 1 < nsteps) STAGE(nb ^ 1, (s + 1) * 32);

    const short* Ab = &As[nb][a_off];
    const short* Bb = &Bs[nb][b_off];
    short8 af0 = *reinterpret_cast<const short8*>(Ab);
    short8 af1 = *reinterpret_cast<const short8*>(Ab + 512);
    short8 bf0 = *reinterpret_cast<const short8*>(Bb);
    short8 bf1 = *reinterpret_cast<const short8*>(Bb + 512);

    acc[0][0] = __builtin_amdgcn_mfma_f32_16x16x32_bf16(af0, bf0, acc[0][0], 0, 0, 0);
    acc[0][1] = __builtin_amdgcn_mfma_f32_16x16x32_bf16(af0, bf1, acc[0][1], 0, 0, 0);
    acc[1][0] = __builtin_amdgcn_mfma_f32_16x16x32_bf16(af1, bf0, acc[1][0], 0, 0, 0);
    acc[1][1] = __builtin_amdgcn_mfma_f32_16x16x32_bf16(af1, bf1, acc[1][1], 0, 0, 0);

    __syncthreads();
  }
#undef STAGE

  const int cl = lane & 15, rh = lane >> 4;
#pragma unroll
  for (int fm = 0; fm < 2; ++fm) {
#pragma unroll
    for (int fn = 0; fn < 2; ++fn) {
      int col = nbase + wc * 32 + fn * 16 + cl;
      float bv = BIAS ? bias[col] : 0.f;
      f32x4 v = acc[fm][fn];
#pragma unroll
      for (int r = 0; r < 4; ++r) {
        int m = mbase + wr * 32 + fm * 16 + rh * 4 + r;
        if (m < M) {
          int b = m / To, to = m % To;
          float x = v[r] + bv;
          if (RELU) x = fmaxf(x, 0.f);
          size_t oi = ((size_t)b * TP_ + t_off_out + to) * (size_t)ldout + col;
          if (OUT_BF16) ((unsigned short*)out)[oi] = f2bf(x);
          else          ((float*)out)[oi] = x;
        }
      }
    }
  }
}

// ---------------------------------------------------------------------------
// Normalize v2 in place (fp32), emit bf16 copy + row norms vn.
// ---------------------------------------------------------------------------
__global__ void v2_norm_vn_k(float* __restrict__ v2, const float* __restrict__ ms,
                             unsigned short* __restrict__ v2bf, float* __restrict__ vn) {
  int r = blockIdx.x, t = threadIdx.x;
  float* row = v2 + (size_t)r * DJ_;
  unsigned short* brow = v2bf + (size_t)r * DJ_;
  float ss = 0.f;
#pragma unroll
  for (int h = 0; h < 2; ++h) {
    int c4 = t + h * 64;
    float4 v = reinterpret_cast<float4*>(row)[c4];
    int c = c4 * 4;
    v.x = (v.x - ms[c+0]) * ms[DJ_+c+0];
    v.y = (v.y - ms[c+1]) * ms[DJ_+c+1];
    v.z = (v.z - ms[c+2]) * ms[DJ_+c+2];
    v.w = (v.w - ms[c+3]) * ms[DJ_+c+3];
    reinterpret_cast<float4*>(row)[c4] = v;
    ushort4_t h4 = { f2bf(v.x), f2bf(v.y), f2bf(v.z), f2bf(v.w) };
    reinterpret_cast<ushort4_t*>(brow)[c4] = h4;
    ss += v.x*v.x + v.y*v.y + v.z*v.z + v.w*v.w;
  }
#pragma unroll
  for (int o = 32; o; o >>= 1) ss += __shfl_down(ss, o, 64);
  if (t == 0) vn[r] = sqrtf(ss);
}

// words normalize -> fp32 (for gram) + bf16 (for attention GEMM)
__global__ void wnorm_k(const float* __restrict__ words, const float* __restrict__ ms,
                        float* __restrict__ wbn, unsigned short* __restrict__ wbnb) {
  int idx = blockIdx.x * 256 + threadIdx.x;
  if (idx >= (B_ * L_ * DJ_) / 4) return;
  int c = (idx & 127) * 4;
  float4 v = reinterpret_cast<const float4*>(words)[idx];
  v.x = (v.x - ms[c+0]) * ms[DJ_+c+0];
  v.y = (v.y - ms[c+1]) * ms[DJ_+c+1];
  v.z = (v.z - ms[c+2]) * ms[DJ_+c+2];
  v.w = (v.w - ms[c+3]) * ms[DJ_+c+3];
  reinterpret_cast<float4*>(wbn)[idx] = v;
  ushort4_t h = { f2bf(v.x), f2bf(v.y), f2bf(v.z), f2bf(v.w) };
  reinterpret_cast<ushort4_t*>(wbnb)[idx] = h;
}

// Per-sentence Gram matrices G[i][l][l'] = w_l . w_l'
__global__ void gram_k(const float* __restrict__ wbn, float* __restrict__ G) {
  __shared__ float sw[L_ * 516];
  int i = blockIdx.x, tid = threadIdx.x;
  for (int idx = tid; idx < L_ * DJ_; idx += 256) {
    int l = idx >> 9, d = idx & 511;
    sw[l * 516 + d] = wbn[(size_t)i * L_ * DJ_ + idx];
  }
  __syncthreads();
  for (int p = tid; p < L_ * L_; p += 256) {
    int l = p / L_, l2 = p % L_;
    const float4* a = reinterpret_cast<const float4*>(&sw[l * 516]);
    const float4* b = reinterpret_cast<const float4*>(&sw[l2 * 516]);
    float acc = 0.f;
    for (int d4 = 0; d4 < 128; ++d4) {
      float4 av = a[d4], bv = b[d4];
      acc += av.x*bv.x + av.y*bv.y + av.z*bv.z + av.w*bv.w;
    }
    G[i * 400 + p] = acc;
  }
}

// ---------------------------------------------------------------------------
// sim kernel
// ---------------------------------------------------------------------------
__global__ __launch_bounds__(256) void sim_k(
    const float* __restrict__ A, const float* __restrict__ G,
    const float* __restrict__ vn, const float* __restrict__ wmask,
    float* __restrict__ pos, float* __restrict__ scores) {
  int j = blockIdx.x, i = blockIdx.y;
  __shared__ float sG[400];
  __shared__ float sm[20];
  __shared__ float red[4];
  int tid = threadIdx.x;
  for (int p = tid; p < 400; p += 256) sG[p] = G[i * 400 + p];
  if (tid < 20) sm[tid] = wmask[i * 20 + tid];
  __syncthreads();

  float simv = -1e30f;
  if (tid < TP_) {
    const float* ar = A + ((size_t)j * TP_ + tid) * 640 + i * 20;
    float a[20], p[20];
    float mx = -1e30f;
#pragma unroll
    for (int l = 0; l < 20; ++l) {
      a[l] = ar[l];
      float lg = (sm[l] > 0.5f) ? LAM_ * a[l] : -1e9f;
      p[l] = lg;
      mx = fmaxf(mx, lg);
    }
    float Z = 0.f;
#pragma unroll
    for (int l = 0; l < 20; ++l) { p[l] = __expf(p[l] - mx); Z += p[l]; }
    float invZ = 1.f / Z, num = 0.f;
#pragma unroll
    for (int l = 0; l < 20; ++l) { p[l] *= invZ; num += p[l] * a[l]; }
    float q2 = 0.f;
#pragma unroll
    for (int l = 0; l < 20; ++l) {
      float gi = 0.f;
#pragma unroll
      for (int l2 = 0; l2 < 20; ++l2) gi += sG[l * 20 + l2] * p[l2];
      q2 += p[l] * gi;
    }
    float vnv = fmaxf(vn[(size_t)j * TP_ + tid], 1e-8f);
    float vsnv = fmaxf(sqrtf(q2), 1e-8f);
    simv = num / (vnv * vsnv);
    if (i == j) pos[i * TP_ + tid] = simv;
  }
  float mv = simv;
#pragma unroll
  for (int o = 32; o; o >>= 1) mv = fmaxf(mv, __shfl_down(mv, o, 64));
  if ((tid & 63) == 0) red[tid >> 6] = mv;
  __syncthreads();
  if (tid == 0)
    scores[i * 32 + j] = fmaxf(fmaxf(red[0], red[1]), fmaxf(red[2], red[3]));
}

// margin ranking loss over scores[32][32]
__global__ void loss_k(const float* __restrict__ scores, float* __restrict__ out) {
  __shared__ float red[16];
  int tid = threadIdx.x;
  int i = tid >> 5, j = tid & 31;
  float s = scores[tid];
  float dgi = scores[i * 32 + i], dgj = scores[j * 32 + j];
  float c = 0.f;
  if (i != j)
    c = fmaxf(0.f, MARGIN_ + s - dgi) + fmaxf(0.f, MARGIN_ + s - dgj);
#pragma unroll
  for (int o = 32; o; o >>= 1) c += __shfl_down(c, o, 64);
  if ((tid & 63) == 0) red[tid >> 6] = c;
  __syncthreads();
  if (tid == 0) {
    float t = 0.f;
    for (int w = 0; w < 16; ++w) t += red[w];
    out[0] = t / 32.f;
  }
}

// ---------------------------------------------------------------------------
extern "C" void kernel_launch(void* const* d_in, const int* in_sizes, int n_in,
                              void* d_out, int out_size, void* d_ws, size_t ws_size,
                              hipStream_t stream) {
  const float* video = (const float*)d_in[0];
  const float* words = (const float*)d_in[1];
  const float* wmask = (const float*)d_in[2];
  const float* c0w = (const float*)d_in[3];
  const float* c0b = (const float*)d_in[4];
  const float* c1w = (const float*)d_in[5];
  const float* c1b = (const float*)d_in[6];
  const float* c2w = (const float*)d_in[7];
  const float* c2b = (const float*)d_in[8];
  const float* pww = (const float*)d_in[9];
  const float* pwb = (const float*)d_in[10];
  float* out = (float*)d_out;
  float* ws  = (float*)d_ws;

  // workspace layout (float units).  Amat overlays vbf.
  float*          W0r    = ws;                                  // bf16 -> 1048576 f
  float*          W1r    = W0r + 1048576;                       // bf16 -> 524288 f
  float*          W2r    = W1r + 524288;                        // 524288 f
  float*          Wpw    = W2r + 524288;                        // bf16 -> 131072 f
  float*          AMvbf  = Wpw + 131072;                        // max(vbf, Amat) = 4485120 f
  float*          vcatb  = AMvbf + 4485120;                     // bf16 -> 1794048 f
  float*          v2     = vcatb + 1794048;                     // 3588096 f
  float*          v2bfp  = v2 + 3588096;                        // bf16 -> 1794048 f
  float*          wbn    = v2bfp + 1794048;                     // 327680 f
  float*          wbnbp  = wbn + 327680;                        // bf16 -> 163840 f
  float*          G      = wbnbp + 163840;                      // 12800
  float*          vn     = G + 12800;                           // 7008
  float*          scores = vn + 7008;                           // 1024
  float*          vpart  = scores + 1024;                       // 512*2048 = 1048576
  float*          vms    = vpart + 1048576;                     // 2048
  float*          v2part = vms + 2048;                          // 876*1024 = 897024
  float*          v2ms   = v2part + 897024;                     // 1024
  float*          wpart  = v2ms + 1024;                         // 80*1024 = 81920
  float*          wms    = wpart + 81920;                       // 1024

  unsigned short* W0     = (unsigned short*)W0r;
  unsigned short* W1     = (unsigned short*)W1r;
  unsigned short* W2     = (unsigned short*)W2r;
  unsigned short* Wp     = (unsigned short*)Wpw;
  unsigned short* vbf    = (unsigned short*)AMvbf;
  float*          Amat   = AMvbf;
  unsigned short* vcb    = (unsigned short*)vcatb;
  unsigned short* v2bf   = (unsigned short*)v2bfp;
  unsigned short* wbnb   = (unsigned short*)wbnbp;

  // weight reorder + bf16 cast (single launch, coalesced)
  reorder_all_k<<<4352, 256, 0, stream>>>(c0w, c1w, c2w, pww, W0, W1, W2, Wp);

  // video BN stats + apply/cast   (8192 rows x 1024 ch)
  stats1_k<<<512, 256, 0, stream>>>(video, vpart, 1024, 8192, 16, 8);
  stats2_k<<<8, 256, 0, stream>>>(vpart, vms, 1024, 512, 1.f / 8192.f);
  vid_bn_cast_k<<<8192, 256, 0, stream>>>(video, vms, vbf);

  // conv tower (bf16 MFMA GEMMs) -> vcat bf16
  mfma_gemm_k<true, true, true><<<dim3(64, 8), 256, 0, stream>>>(
      vbf, W0, c0b, vcb, 262144, 0, 2048, T0_, 32 * T0_, 0, 512, 4096);
  mfma_gemm_k<true, true, true><<<dim3(31, 8), 256, 0, stream>>>(
      vcb, W1, c1b, vcb, 112128, 0, 1024, T1_, 32 * T1_, T0_, 512, 2048);
  mfma_gemm_k<true, true, true><<<dim3(15, 8), 256, 0, stream>>>(
      vcb, W2, c2b, vcb, 112128, 65024, 1024, T2_, 32 * T2_, T0_ + T1_, 512, 2048);
  // pointwise conv -> v2 fp32
  mfma_gemm_k<false, true, false><<<dim3(110, 8), 256, 0, stream>>>(
      vcb, Wp, pwb, v2, 112128, 0, 512, TP_, 32 * TP_, 0, 512, 512);

  // v2 BN (+ bf16 copy + row norms)   (7008 rows x 512 ch)
  stats1_k<<<438, 256, 0, stream>>>(v2, v2part, 512, 7008, 16, 7);
  stats2_k<<<4, 256, 0, stream>>>(v2part, v2ms, 512, 876, 1.f / 7008.f);
  v2_norm_vn_k<<<7008, 64, 0, stream>>>(v2, v2ms, v2bf, vn);

  // words BN   (640 rows x 512 ch)
  stats1_k<<<40, 256, 0, stream>>>(words, wpart, 512, 640, 16, 7);
  stats2_k<<<4, 256, 0, stream>>>(wpart, wms, 512, 80, 1.f / 640.f);
  wnorm_k<<<(81920 + 255) / 256, 256, 0, stream>>>(words, wms, wbn, wbnb);
  gram_k<<<32, 256, 0, stream>>>(wbn, G);

  // A[(j,t)][(i,l)] = v . w  (M=7008, N=640, K=512) -> Amat fp32 (overlays vbf)
  mfma_gemm_k<false, false, false><<<dim3(110, 10), 256, 0, stream>>>(
      v2bf, wbnb, nullptr, Amat, 112128, 0, 512, TP_, 32 * TP_, 0, 640, 512);

  // fused softmax / cosine-sim / scores / positive_map
  sim_k<<<dim3(32, 32), 256, 0, stream>>>(Amat, G, vn, wmask, out + 1, scores);
  loss_k<<<1, 1024, 0, stream>>>(scores, out);
}

// Round 5
// 245.808 us; speedup vs baseline: 3.4036x; 1.1022x over previous
//
#include <hip/hip_runtime.h>
#include <math.h>

// Problem constants
#define B_   32
#define T_   256
#define DV_  1024
#define DJ_  512
#define L_   20
#define T0_  127
#define T1_  62
#define T2_  30
#define TP_  219          // 127+62+30
#define LAM_ 4.0f
#define MARGIN_ 0.1f

typedef __attribute__((ext_vector_type(8))) short short8;
typedef __attribute__((ext_vector_type(4))) float f32x4;

static __device__ __forceinline__ unsigned short f2bf(float f) {
  union { float f; unsigned u; } v; v.f = f;
  unsigned r = v.u + 0x7fff + ((v.u >> 16) & 1);   // round-to-nearest-even
  return (unsigned short)(r >> 16);
}

struct ushort4_t { unsigned short x, y, z, w; };

#define GLOAD_LDS16(gp, lp)                                                      \
  __builtin_amdgcn_global_load_lds(                                              \
      (const __attribute__((address_space(1))) void*)(gp),                       \
      (__attribute__((address_space(3))) void*)(lp), 16, 0, 0)

// ---------------------------------------------------------------------------
// Weight reorder+cast, coalesced: thread = (co,ci), float4 read of 4 taps,
// 4 coalesced ushort stores at stride Cin.  pw = straight cast.
// ---------------------------------------------------------------------------
__global__ void reorder_all_k(const float* __restrict__ c0w, const float* __restrict__ c1w,
                              const float* __restrict__ c2w, const float* __restrict__ pww,
                              unsigned short* __restrict__ W0, unsigned short* __restrict__ W1,
                              unsigned short* __restrict__ W2, unsigned short* __restrict__ Wp) {
  int bid = blockIdx.x;
  if (bid < 2048) {            // conv0: 512*1024 (co,ci) pairs
    int idx = bid * 256 + threadIdx.x;
    int co = idx >> 10, ci = idx & 1023;
    float4 w = *reinterpret_cast<const float4*>(c0w + (size_t)idx * 4);
    unsigned short* d = W0 + (size_t)co * 4096 + ci;
    d[0] = f2bf(w.x); d[1024] = f2bf(w.y); d[2048] = f2bf(w.z); d[3072] = f2bf(w.w);
  } else if (bid < 3072) {     // conv1: 512*512
    int idx = (bid - 2048) * 256 + threadIdx.x;
    int co = idx >> 9, ci = idx & 511;
    float4 w = *reinterpret_cast<const float4*>(c1w + (size_t)idx * 4);
    unsigned short* d = W1 + (size_t)co * 2048 + ci;
    d[0] = f2bf(w.x); d[512] = f2bf(w.y); d[1024] = f2bf(w.z); d[1536] = f2bf(w.w);
  } else if (bid < 4096) {     // conv2: 512*512
    int idx = (bid - 3072) * 256 + threadIdx.x;
    int co = idx >> 9, ci = idx & 511;
    float4 w = *reinterpret_cast<const float4*>(c2w + (size_t)idx * 4);
    unsigned short* d = W2 + (size_t)co * 2048 + ci;
    d[0] = f2bf(w.x); d[512] = f2bf(w.y); d[1024] = f2bf(w.z); d[1536] = f2bf(w.w);
  } else {                     // pw: identity cast, 262144 elems / 4
    int idx = (bid - 4096) * 256 + threadIdx.x;
    float4 v = *reinterpret_cast<const float4*>(pww + (size_t)idx * 4);
    ushort4_t h = { f2bf(v.x), f2bf(v.y), f2bf(v.z), f2bf(v.w) };
    reinterpret_cast<ushort4_t*>(Wp)[idx] = h;
  }
}

// ---------------------------------------------------------------------------
// BatchNorm stats, two stage, deterministic, highly parallel.
// ---------------------------------------------------------------------------
__global__ void stats1_k(const float* __restrict__ x, float* __restrict__ part,
                         int C, int rows, int rpg, int cpgShift) {
  int cpg  = 1 << cpgShift;                 // C/4
  int c4   = threadIdx.x & (cpg - 1);
  int rsub = threadIdx.x >> cpgShift;
  int nsub = 256 >> cpgShift;
  int r0 = blockIdx.x * rpg + rsub;
  int r1 = min(blockIdx.x * rpg + rpg, rows);
  float4 s = {0.f,0.f,0.f,0.f}, q = {0.f,0.f,0.f,0.f};
  for (int r = r0; r < r1; r += nsub) {
    float4 v = *reinterpret_cast<const float4*>(&x[(size_t)r * C + c4 * 4]);
    s.x += v.x; s.y += v.y; s.z += v.z; s.w += v.w;
    q.x += v.x*v.x; q.y += v.y*v.y; q.z += v.z*v.z; q.w += v.w*v.w;
  }
  float* ps = part + ((size_t)blockIdx.x * nsub + rsub) * 2 * C;
  reinterpret_cast<float4*>(ps)[c4] = s;
  reinterpret_cast<float4*>(ps + C)[c4] = q;
}

// Stage 2: block handles 128 channels (32 float4); 8 g-stripes; LDS combine.
__global__ void stats2_k(const float* __restrict__ part, float* __restrict__ ms,
                         int C, int ng, float inv_n) {
  __shared__ float4 sS[8][33], sQ[8][33];
  int c4l = threadIdx.x & 31;
  int gs  = threadIdx.x >> 5;
  int c4  = blockIdx.x * 32 + c4l;          // float4 channel index
  float4 s = {0.f,0.f,0.f,0.f}, q = {0.f,0.f,0.f,0.f};
  for (int g = gs; g < ng; g += 8) {
    const float4* ps = reinterpret_cast<const float4*>(part + (size_t)g * 2 * C);
    float4 a = ps[c4];
    float4 b = ps[(C >> 2) + c4];
    s.x += a.x; s.y += a.y; s.z += a.z; s.w += a.w;
    q.x += b.x; q.y += b.y; q.z += b.z; q.w += b.w;
  }
  sS[gs][c4l] = s; sQ[gs][c4l] = q;
  __syncthreads();
  if (gs == 0) {
    float4 S = sS[0][c4l], Q = sQ[0][c4l];
#pragma unroll
    for (int k = 1; k < 8; ++k) {
      float4 a = sS[k][c4l], b = sQ[k][c4l];
      S.x += a.x; S.y += a.y; S.z += a.z; S.w += a.w;
      Q.x += b.x; Q.y += b.y; Q.z += b.z; Q.w += b.w;
    }
    int c = c4 * 4;
    float m0 = S.x * inv_n, m1 = S.y * inv_n, m2 = S.z * inv_n, m3 = S.w * inv_n;
    ms[c+0] = m0; ms[C+c+0] = rsqrtf(Q.x * inv_n - m0*m0 + 1e-5f);
    ms[c+1] = m1; ms[C+c+1] = rsqrtf(Q.y * inv_n - m1*m1 + 1e-5f);
    ms[c+2] = m2; ms[C+c+2] = rsqrtf(Q.z * inv_n - m2*m2 + 1e-5f);
    ms[c+3] = m3; ms[C+c+3] = rsqrtf(Q.w * inv_n - m3*m3 + 1e-5f);
  }
}

// video BN apply + cast to bf16
__global__ void vid_bn_cast_k(const float* __restrict__ video,
                              const float* __restrict__ ms,
                              unsigned short* __restrict__ vbf) {
  int i4 = blockIdx.x * 256 + threadIdx.x;
  float4 v = reinterpret_cast<const float4*>(video)[i4];
  int c = (i4 & 255) * 4;
  v.x = (v.x - ms[c+0]) * ms[1024+c+0];
  v.y = (v.y - ms[c+1]) * ms[1024+c+1];
  v.z = (v.z - ms[c+2]) * ms[1024+c+2];
  v.w = (v.w - ms[c+3]) * ms[1024+c+3];
  ushort4_t h = { f2bf(v.x), f2bf(v.y), f2bf(v.z), f2bf(v.w) };
  reinterpret_cast<ushort4_t*>(vbf)[i4] = h;
}

// ---------------------------------------------------------------------------
// MFMA bf16 GEMM.  BM=64, BN=64, BK=32, 256 thr = 4 waves (2x2), wave tile
// 32x32 (2x2 frags of 16x16x32).  Source-side chunk swizzle (involution on
// the read side) -> low bank aliasing.  PARTIAL: blockIdx.z = K-split index,
// writes fp32 dense partial [split][m][ldout] (no bias/relu).
// ---------------------------------------------------------------------------
template<bool RELU, bool BIAS, bool OUT_BF16, bool PARTIAL>
__global__ __launch_bounds__(256) void mfma_gemm_k(
    const unsigned short* __restrict__ xin, const unsigned short* __restrict__ Wr,
    const float* __restrict__ bias, void* __restrict__ out,
    int b_stride, int row_off, int row_t_stride,
    int To, int M, int t_off_out, int ldout, int Ktot, int Kloc)
{
  __shared__ __align__(16) short As[2][64 * 32];
  __shared__ __align__(16) short Bs[2][64 * 32];

  const int tid  = threadIdx.x;
  const int lane = tid & 63;
  const int wv   = tid >> 6;
  const int wr   = wv >> 1;
  const int wc   = wv & 1;
  const int mbase = blockIdx.x * 64;
  const int nbase = blockIdx.y * 64;
  const int kstart = PARTIAL ? blockIdx.z * Kloc : 0;

  const int srow = tid >> 2;
  const int sb   = (((tid & 3) ^ ((srow ^ (srow >> 2)) & 3))) * 8;
  int ma = min(mbase + srow, M - 1);
  int b0 = ma / To, t0 = ma % To;
  const unsigned short* agp = xin + (size_t)b0 * b_stride + row_off
                              + (size_t)t0 * row_t_stride + sb + kstart;
  const unsigned short* bgp = Wr + (size_t)(nbase + srow) * Ktot + sb + kstart;

  f32x4 acc[2][2] = {};
  const int nsteps = Kloc >> 5;

#define STAGE(buf, k0)                                        \
  do {                                                        \
    GLOAD_LDS16(agp + (k0), &As[buf][wv * 512]);              \
    GLOAD_LDS16(bgp + (k0), &Bs[buf][wv * 512]);              \
  } while (0)

  STAGE(0, 0);
  __syncthreads();

  const int rsw   = (lane ^ (lane >> 2)) & 3;
  const int chunk = ((lane >> 4) ^ rsw) * 8;
  const int a_off = (wr * 32 + (lane & 15)) * 32 + chunk;
  const int b_off = (wc * 32 + (lane & 15)) * 32 + chunk;

  for (int s = 0; s < nsteps; ++s) {
    const int nb = s & 1;
    if (s + 1 < nsteps) STAGE(nb ^ 1, (s + 1) * 32);

    const short* Ab = &As[nb][a_off];
    const short* Bb = &Bs[nb][b_off];
    short8 af0 = *reinterpret_cast<const short8*>(Ab);
    short8 af1 = *reinterpret_cast<const short8*>(Ab + 512);
    short8 bf0 = *reinterpret_cast<const short8*>(Bb);
    short8 bf1 = *reinterpret_cast<const short8*>(Bb + 512);

    acc[0][0] = __builtin_amdgcn_mfma_f32_16x16x32_bf16(af0, bf0, acc[0][0], 0, 0, 0);
    acc[0][1] = __builtin_amdgcn_mfma_f32_16x16x32_bf16(af0, bf1, acc[0][1], 0, 0, 0);
    acc[1][0] = __builtin_amdgcn_mfma_f32_16x16x32_bf16(af1, bf0, acc[1][0], 0, 0, 0);
    acc[1][1] = __builtin_amdgcn_mfma_f32_16x16x32_bf16(af1, bf1, acc[1][1], 0, 0, 0);

    __syncthreads();
  }
#undef STAGE

  const int cl = lane & 15, rh = lane >> 4;
#pragma unroll
  for (int fm = 0; fm < 2; ++fm) {
#pragma unroll
    for (int fn = 0; fn < 2; ++fn) {
      int col = nbase + wc * 32 + fn * 16 + cl;
      float bv = BIAS ? bias[col] : 0.f;
      f32x4 v = acc[fm][fn];
#pragma unroll
      for (int r = 0; r < 4; ++r) {
        int m = mbase + wr * 32 + fm * 16 + rh * 4 + r;
        if (m < M) {
          if (PARTIAL) {
            float* pout = (float*)out + (size_t)blockIdx.z * ((size_t)M * ldout);
            pout[(size_t)m * ldout + col] = v[r];
          } else {
            int b = m / To, to = m % To;
            float x = v[r] + bv;
            if (RELU) x = fmaxf(x, 0.f);
            size_t oi = ((size_t)b * TP_ + t_off_out + to) * (size_t)ldout + col;
            if (OUT_BF16) ((unsigned short*)out)[oi] = f2bf(x);
            else          ((float*)out)[oi] = x;
          }
        }
      }
    }
  }
}

// ---------------------------------------------------------------------------
// K-split reduce: sum S partials [S][M][512], +bias, relu, bf16, scatter to
// vcat rows.  thread = one float4 of one row.
// ---------------------------------------------------------------------------
template<int S>
__global__ void reduce_conv_k(const float* __restrict__ part, const float* __restrict__ bias,
                              unsigned short* __restrict__ outb,
                              int M, int To, int t_off_out) {
  int idx = blockIdx.x * 256 + threadIdx.x;      // over M*128 float4s
  int m = idx >> 7, n4 = idx & 127;
  if (m >= M) return;
  size_t off = (size_t)m * 512 + n4 * 4;
  float4 a = *reinterpret_cast<const float4*>(part + off);
#pragma unroll
  for (int s = 1; s < S; ++s) {
    float4 b = *reinterpret_cast<const float4*>(part + (size_t)s * M * 512 + off);
    a.x += b.x; a.y += b.y; a.z += b.z; a.w += b.w;
  }
  float4 bv = *reinterpret_cast<const float4*>(bias + n4 * 4);
  a.x = fmaxf(a.x + bv.x, 0.f);
  a.y = fmaxf(a.y + bv.y, 0.f);
  a.z = fmaxf(a.z + bv.z, 0.f);
  a.w = fmaxf(a.w + bv.w, 0.f);
  int b_ = m / To, to = m % To;
  ushort4_t h = { f2bf(a.x), f2bf(a.y), f2bf(a.z), f2bf(a.w) };
  reinterpret_cast<ushort4_t*>(outb + ((size_t)b_ * TP_ + t_off_out + to) * 512)[n4] = h;
}

// ---------------------------------------------------------------------------
// Normalize v2 in place (fp32), emit bf16 copy + row norms vn.
// ---------------------------------------------------------------------------
__global__ void v2_norm_vn_k(float* __restrict__ v2, const float* __restrict__ ms,
                             unsigned short* __restrict__ v2bf, float* __restrict__ vn) {
  int r = blockIdx.x, t = threadIdx.x;
  float* row = v2 + (size_t)r * DJ_;
  unsigned short* brow = v2bf + (size_t)r * DJ_;
  float ss = 0.f;
#pragma unroll
  for (int h = 0; h < 2; ++h) {
    int c4 = t + h * 64;
    float4 v = reinterpret_cast<float4*>(row)[c4];
    int c = c4 * 4;
    v.x = (v.x - ms[c+0]) * ms[DJ_+c+0];
    v.y = (v.y - ms[c+1]) * ms[DJ_+c+1];
    v.z = (v.z - ms[c+2]) * ms[DJ_+c+2];
    v.w = (v.w - ms[c+3]) * ms[DJ_+c+3];
    reinterpret_cast<float4*>(row)[c4] = v;
    ushort4_t h4 = { f2bf(v.x), f2bf(v.y), f2bf(v.z), f2bf(v.w) };
    reinterpret_cast<ushort4_t*>(brow)[c4] = h4;
    ss += v.x*v.x + v.y*v.y + v.z*v.z + v.w*v.w;
  }
#pragma unroll
  for (int o = 32; o; o >>= 1) ss += __shfl_down(ss, o, 64);
  if (t == 0) vn[r] = sqrtf(ss);
}

// words normalize -> fp32 (for gram) + bf16 (for attention GEMM)
__global__ void wnorm_k(const float* __restrict__ words, const float* __restrict__ ms,
                        float* __restrict__ wbn, unsigned short* __restrict__ wbnb) {
  int idx = blockIdx.x * 256 + threadIdx.x;
  if (idx >= (B_ * L_ * DJ_) / 4) return;
  int c = (idx & 127) * 4;
  float4 v = reinterpret_cast<const float4*>(words)[idx];
  v.x = (v.x - ms[c+0]) * ms[DJ_+c+0];
  v.y = (v.y - ms[c+1]) * ms[DJ_+c+1];
  v.z = (v.z - ms[c+2]) * ms[DJ_+c+2];
  v.w = (v.w - ms[c+3]) * ms[DJ_+c+3];
  reinterpret_cast<float4*>(wbn)[idx] = v;
  ushort4_t h = { f2bf(v.x), f2bf(v.y), f2bf(v.z), f2bf(v.w) };
  reinterpret_cast<ushort4_t*>(wbnb)[idx] = h;
}

// Per-sentence Gram matrices G[i][l][l'] = w_l . w_l'
__global__ void gram_k(const float* __restrict__ wbn, float* __restrict__ G) {
  __shared__ float sw[L_ * 516];
  int i = blockIdx.x, tid = threadIdx.x;
  for (int idx = tid; idx < L_ * DJ_; idx += 256) {
    int l = idx >> 9, d = idx & 511;
    sw[l * 516 + d] = wbn[(size_t)i * L_ * DJ_ + idx];
  }
  __syncthreads();
  for (int p = tid; p < L_ * L_; p += 256) {
    int l = p / L_, l2 = p % L_;
    const float4* a = reinterpret_cast<const float4*>(&sw[l * 516]);
    const float4* b = reinterpret_cast<const float4*>(&sw[l2 * 516]);
    float acc = 0.f;
    for (int d4 = 0; d4 < 128; ++d4) {
      float4 av = a[d4], bv = b[d4];
      acc += av.x*bv.x + av.y*bv.y + av.z*bv.z + av.w*bv.w;
    }
    G[i * 400 + p] = acc;
  }
}

// ---------------------------------------------------------------------------
// sim kernel
// ---------------------------------------------------------------------------
__global__ __launch_bounds__(256) void sim_k(
    const float* __restrict__ A, const float* __restrict__ G,
    const float* __restrict__ vn, const float* __restrict__ wmask,
    float* __restrict__ pos, float* __restrict__ scores) {
  int j = blockIdx.x, i = blockIdx.y;
  __shared__ float sG[400];
  __shared__ float sm[20];
  __shared__ float red[4];
  int tid = threadIdx.x;
  for (int p = tid; p < 400; p += 256) sG[p] = G[i * 400 + p];
  if (tid < 20) sm[tid] = wmask[i * 20 + tid];
  __syncthreads();

  float simv = -1e30f;
  if (tid < TP_) {
    const float* ar = A + ((size_t)j * TP_ + tid) * 640 + i * 20;
    float a[20], p[20];
    float mx = -1e30f;
#pragma unroll
    for (int l = 0; l < 20; ++l) {
      a[l] = ar[l];
      float lg = (sm[l] > 0.5f) ? LAM_ * a[l] : -1e9f;
      p[l] = lg;
      mx = fmaxf(mx, lg);
    }
    float Z = 0.f;
#pragma unroll
    for (int l = 0; l < 20; ++l) { p[l] = __expf(p[l] - mx); Z += p[l]; }
    float invZ = 1.f / Z, num = 0.f;
#pragma unroll
    for (int l = 0; l < 20; ++l) { p[l] *= invZ; num += p[l] * a[l]; }
    float q2 = 0.f;
#pragma unroll
    for (int l = 0; l < 20; ++l) {
      float gi = 0.f;
#pragma unroll
      for (int l2 = 0; l2 < 20; ++l2) gi += sG[l * 20 + l2] * p[l2];
      q2 += p[l] * gi;
    }
    float vnv = fmaxf(vn[(size_t)j * TP_ + tid], 1e-8f);
    float vsnv = fmaxf(sqrtf(q2), 1e-8f);
    simv = num / (vnv * vsnv);
    if (i == j) pos[i * TP_ + tid] = simv;
  }
  float mv = simv;
#pragma unroll
  for (int o = 32; o; o >>= 1) mv = fmaxf(mv, __shfl_down(mv, o, 64));
  if ((tid & 63) == 0) red[tid >> 6] = mv;
  __syncthreads();
  if (tid == 0)
    scores[i * 32 + j] = fmaxf(fmaxf(red[0], red[1]), fmaxf(red[2], red[3]));
}

// margin ranking loss over scores[32][32]
__global__ void loss_k(const float* __restrict__ scores, float* __restrict__ out) {
  __shared__ float red[16];
  int tid = threadIdx.x;
  int i = tid >> 5, j = tid & 31;
  float s = scores[tid];
  float dgi = scores[i * 32 + i], dgj = scores[j * 32 + j];
  float c = 0.f;
  if (i != j)
    c = fmaxf(0.f, MARGIN_ + s - dgi) + fmaxf(0.f, MARGIN_ + s - dgj);
#pragma unroll
  for (int o = 32; o; o >>= 1) c += __shfl_down(c, o, 64);
  if ((tid & 63) == 0) red[tid >> 6] = c;
  __syncthreads();
  if (tid == 0) {
    float t = 0.f;
    for (int w = 0; w < 16; ++w) t += red[w];
    out[0] = t / 32.f;
  }
}

// ---------------------------------------------------------------------------
extern "C" void kernel_launch(void* const* d_in, const int* in_sizes, int n_in,
                              void* d_out, int out_size, void* d_ws, size_t ws_size,
                              hipStream_t stream) {
  const float* video = (const float*)d_in[0];
  const float* words = (const float*)d_in[1];
  const float* wmask = (const float*)d_in[2];
  const float* c0w = (const float*)d_in[3];
  const float* c0b = (const float*)d_in[4];
  const float* c1w = (const float*)d_in[5];
  const float* c1b = (const float*)d_in[6];
  const float* c2w = (const float*)d_in[7];
  const float* c2b = (const float*)d_in[8];
  const float* pww = (const float*)d_in[9];
  const float* pwb = (const float*)d_in[10];
  float* out = (float*)d_out;
  float* ws  = (float*)d_ws;

  // workspace layout (float units).
  // P (K-split partial scratch, 8323072 f) OVERLAYS the v2.. region: those
  // arrays are only written after the last conv reduce; vpart/vms (inside P)
  // are dead before conv0 starts.  Amat overlays vbf (dead after conv0).
  float*          W0r    = ws;                                  // 1048576
  float*          W1r    = W0r + 1048576;                       // 524288
  float*          W2r    = W1r + 524288;                        // 524288
  float*          Wpw    = W2r + 524288;                        // 131072
  float*          AMvbf  = Wpw + 131072;                        // 4485120  (vbf | Amat)
  float*          vcatb  = AMvbf + 4485120;                     // 1794048  (bf16 vcat)
  float*          Pbuf   = vcatb + 1794048;                     // 8323072  (overlay start)
  float*          v2     = Pbuf;                                // 3588096
  float*          v2bfp  = v2 + 3588096;                        // 1794048
  float*          wbn    = v2bfp + 1794048;                     // 327680
  float*          wbnbp  = wbn + 327680;                        // 163840
  float*          G      = wbnbp + 163840;                      // 12800
  float*          vn     = G + 12800;                           // 7008
  float*          scores = vn + 7008;                           // 1024
  float*          vpart  = scores + 1024;                       // 1048576
  float*          vms    = vpart + 1048576;                     // 2048
  float*          v2part = vms + 2048;                          // 897024
  float*          v2ms   = v2part + 897024;                     // 1024
  float*          wpart  = v2ms + 1024;                         // 81920
  float*          wms    = wpart + 81920;                       // 1024
  // total span = max(Pbuf+8323072, wms+1024) = 16830464 floats ≈ 67.3 MB

  unsigned short* W0     = (unsigned short*)W0r;
  unsigned short* W1     = (unsigned short*)W1r;
  unsigned short* W2     = (unsigned short*)W2r;
  unsigned short* Wp     = (unsigned short*)Wpw;
  unsigned short* vbf    = (unsigned short*)AMvbf;
  float*          Amat   = AMvbf;
  unsigned short* vcb    = (unsigned short*)vcatb;
  unsigned short* v2bf   = (unsigned short*)v2bfp;
  unsigned short* wbnb   = (unsigned short*)wbnbp;

  // weight reorder + bf16 cast (single launch, coalesced)
  reorder_all_k<<<4352, 256, 0, stream>>>(c0w, c1w, c2w, pww, W0, W1, W2, Wp);

  // video BN stats + apply/cast   (8192 rows x 1024 ch)
  stats1_k<<<512, 256, 0, stream>>>(video, vpart, 1024, 8192, 16, 8);
  stats2_k<<<8, 256, 0, stream>>>(vpart, vms, 1024, 512, 1.f / 8192.f);
  vid_bn_cast_k<<<8192, 256, 0, stream>>>(video, vms, vbf);

  // ---- conv tower, K-split for occupancy, fp32 partials -> reduce ----
  // conv0: M=4064, K=4096 -> 4 x 1024
  mfma_gemm_k<false, false, false, true><<<dim3(64, 8, 4), 256, 0, stream>>>(
      vbf, W0, nullptr, Pbuf, 262144, 0, 2048, T0_, 32 * T0_, 0, 512, 4096, 1024);
  reduce_conv_k<4><<<2032, 256, 0, stream>>>(Pbuf, c0b, vcb, 32 * T0_, T0_, 0);
  // conv1: M=1984, K=2048 -> 4 x 512
  mfma_gemm_k<false, false, false, true><<<dim3(31, 8, 4), 256, 0, stream>>>(
      vcb, W1, nullptr, Pbuf, 112128, 0, 1024, T1_, 32 * T1_, 0, 512, 2048, 512);
  reduce_conv_k<4><<<992, 256, 0, stream>>>(Pbuf, c1b, vcb, 32 * T1_, T1_, T0_);
  // conv2: M=960, K=2048 -> 8 x 256
  mfma_gemm_k<false, false, false, true><<<dim3(15, 8, 8), 256, 0, stream>>>(
      vcb, W2, nullptr, Pbuf, 112128, 65024, 1024, T2_, 32 * T2_, 0, 512, 2048, 256);
  reduce_conv_k<8><<<480, 256, 0, stream>>>(Pbuf, c2b, vcb, 32 * T2_, T2_, T0_ + T1_);

  // pointwise conv -> v2 fp32 (880 blocks, ~3.4/CU: unsplit)
  mfma_gemm_k<false, true, false, false><<<dim3(110, 8), 256, 0, stream>>>(
      vcb, Wp, pwb, v2, 112128, 0, 512, TP_, 32 * TP_, 0, 512, 512, 512);

  // v2 BN (+ bf16 copy + row norms)   (7008 rows x 512 ch)
  stats1_k<<<438, 256, 0, stream>>>(v2, v2part, 512, 7008, 16, 7);
  stats2_k<<<4, 256, 0, stream>>>(v2part, v2ms, 512, 876, 1.f / 7008.f);
  v2_norm_vn_k<<<7008, 64, 0, stream>>>(v2, v2ms, v2bf, vn);

  // words BN   (640 rows x 512 ch)
  stats1_k<<<40, 256, 0, stream>>>(words, wpart, 512, 640, 16, 7);
  stats2_k<<<4, 256, 0, stream>>>(wpart, wms, 512, 80, 1.f / 640.f);
  wnorm_k<<<(81920 + 255) / 256, 256, 0, stream>>>(words, wms, wbn, wbnb);
  gram_k<<<32, 256, 0, stream>>>(wbn, G);

  // A[(j,t)][(i,l)] = v . w  (M=7008, N=640, K=512) -> Amat fp32 (overlays vbf)
  mfma_gemm_k<false, false, false, false><<<dim3(110, 10), 256, 0, stream>>>(
      v2bf, wbnb, nullptr, Amat, 112128, 0, 512, TP_, 32 * TP_, 0, 640, 512, 512);

  // fused softmax / cosine-sim / scores / positive_map
  sim_k<<<dim3(32, 32), 256, 0, stream>>>(Amat, G, vn, wmask, out + 1, scores);
  loss_k<<<1, 1024, 0, stream>>>(scores, out);
}